// Round 1
// baseline (7387.601 us; speedup 1.0000x reference)
//
#include <hip/hip_runtime.h>
#include <hip/hip_bf16.h>
#include <math.h>

#define N_NODES 50000
#define N_EDGES 1600000
#define ET (N_EDGES + N_NODES)   // with self loops
#define IN_C 165
#define HID 256
#define HEADS 8
#define C1 32
#define OUT_C 2
#define NEG_SLOPE 0.2f

// ---- monotone float<->uint encoding for atomicMax on floats ----
__device__ inline unsigned enc_f(float x) {
    unsigned u = __float_as_uint(x);
    return (u >> 31) ? ~u : (u | 0x80000000u);
}
__device__ inline float dec_f(unsigned u) {
    return (u >> 31) ? __uint_as_float(u ^ 0x80000000u) : __uint_as_float(~u);
}
__device__ inline float lrelu(float v) { return v > 0.f ? v : NEG_SLOPE * v; }

// ============ Layer 1 GEMM: h1[N,256] = x[N,165] @ W1[165,256] ============
__global__ __launch_bounds__(256) void gemm1_kernel(
        const float* __restrict__ x, const float* __restrict__ W,
        float* __restrict__ h) {
    __shared__ float xs[32 * IN_C];
    const int row0 = blockIdx.x * 32;
    const int colb = blockIdx.y * 64;
    const int tid = threadIdx.x;
    for (int idx = tid; idx < 32 * IN_C; idx += 256) {
        int r = idx / IN_C, c = idx - r * IN_C;
        int gr = row0 + r;
        xs[idx] = (gr < N_NODES) ? x[gr * IN_C + c] : 0.f;
    }
    __syncthreads();
    const int r = tid & 31;
    const int cg = tid >> 5;           // 0..7
    const int c0 = colb + cg * 8;
    float acc[8] = {0.f, 0.f, 0.f, 0.f, 0.f, 0.f, 0.f, 0.f};
    for (int k = 0; k < IN_C; ++k) {
        float xv = xs[r * IN_C + k];
        const float* w = W + k * HID + c0;
        float4 w0 = *(const float4*)(w);
        float4 w1 = *(const float4*)(w + 4);
        acc[0] += xv * w0.x; acc[1] += xv * w0.y;
        acc[2] += xv * w0.z; acc[3] += xv * w0.w;
        acc[4] += xv * w1.x; acc[5] += xv * w1.y;
        acc[6] += xv * w1.z; acc[7] += xv * w1.w;
    }
    int gr = row0 + r;
    if (gr < N_NODES) {
        float* o = h + gr * HID + c0;
        *(float4*)(o)     = make_float4(acc[0], acc[1], acc[2], acc[3]);
        *(float4*)(o + 4) = make_float4(acc[4], acc[5], acc[6], acc[7]);
    }
}

// ============ per-node attention logits, layer 1 ============
__global__ __launch_bounds__(256) void att1_kernel(
        const float* __restrict__ h, const float* __restrict__ att_src,
        const float* __restrict__ att_dst,
        float* __restrict__ a_src, float* __restrict__ a_dst) {
    int t = blockIdx.x * 256 + threadIdx.x;   // t = n*8 + head
    if (t >= N_NODES * HEADS) return;
    int hd = t & 7;
    const float* hp = h + (size_t)t * C1;     // n*256 + hd*32 == t*32
    const float* as = att_src + hd * C1;
    const float* ad = att_dst + hd * C1;
    float s = 0.f, d = 0.f;
    for (int c = 0; c < C1; c += 4) {
        float4 hv = *(const float4*)(hp + c);
        float4 av = *(const float4*)(as + c);
        float4 dv = *(const float4*)(ad + c);
        s += hv.x * av.x + hv.y * av.y + hv.z * av.z + hv.w * av.w;
        d += hv.x * dv.x + hv.y * dv.y + hv.z * dv.z + hv.w * dv.w;
    }
    a_src[t] = s;
    a_dst[t] = d;
}

// ============ edge pass 1: segment max (layer 1, 8 heads) ============
__global__ __launch_bounds__(256) void edge_max1_kernel(
        const int* __restrict__ src, const int* __restrict__ dst,
        const float* __restrict__ a_src, const float* __restrict__ a_dst,
        unsigned* __restrict__ m1) {
    int e = blockIdx.x * 256 + threadIdx.x;
    if (e >= ET) return;
    int s, d;
    if (e < N_EDGES) { s = src[e]; d = dst[e]; } else { s = d = e - N_EDGES; }
    float4 s0 = *(const float4*)(a_src + s * 8);
    float4 s1 = *(const float4*)(a_src + s * 8 + 4);
    float4 d0 = *(const float4*)(a_dst + d * 8);
    float4 d1 = *(const float4*)(a_dst + d * 8 + 4);
    float el[8] = {s0.x + d0.x, s0.y + d0.y, s0.z + d0.z, s0.w + d0.w,
                   s1.x + d1.x, s1.y + d1.y, s1.z + d1.z, s1.w + d1.w};
    unsigned* mp = m1 + d * 8;
    #pragma unroll
    for (int h = 0; h < 8; ++h) atomicMax(mp + h, enc_f(lrelu(el[h])));
}

// ============ edge pass 2: segment sum of exp (layer 1) ============
__global__ __launch_bounds__(256) void edge_sum1_kernel(
        const int* __restrict__ src, const int* __restrict__ dst,
        const float* __restrict__ a_src, const float* __restrict__ a_dst,
        const unsigned* __restrict__ m1, float* __restrict__ d1) {
    int e = blockIdx.x * 256 + threadIdx.x;
    if (e >= ET) return;
    int s, d;
    if (e < N_EDGES) { s = src[e]; d = dst[e]; } else { s = d = e - N_EDGES; }
    float4 s0 = *(const float4*)(a_src + s * 8);
    float4 s1 = *(const float4*)(a_src + s * 8 + 4);
    float4 d0 = *(const float4*)(a_dst + d * 8);
    float4 d1v = *(const float4*)(a_dst + d * 8 + 4);
    float el[8] = {s0.x + d0.x, s0.y + d0.y, s0.z + d0.z, s0.w + d0.w,
                   s1.x + d1v.x, s1.y + d1v.y, s1.z + d1v.z, s1.w + d1v.w};
    #pragma unroll
    for (int h = 0; h < 8; ++h) {
        float m = dec_f(m1[d * 8 + h]);
        atomicAdd(d1 + d * 8 + h, __expf(lrelu(el[h]) - m));
    }
}

// ============ aggregation layer 1: 64 lanes per edge, 4 ch per lane ============
__global__ __launch_bounds__(256) void agg1_kernel(
        const int* __restrict__ src, const int* __restrict__ dst,
        const float* __restrict__ a_src, const float* __restrict__ a_dst,
        const unsigned* __restrict__ m1, const float* __restrict__ d1,
        const float* __restrict__ h1, float* __restrict__ out) {
    long long t = (long long)blockIdx.x * 256 + threadIdx.x;
    int e = (int)(t >> 6);
    int l = (int)(t & 63);
    if (e >= ET) return;
    int s, d;
    if (e < N_EDGES) { s = src[e]; d = dst[e]; } else { s = d = e - N_EDGES; }
    int hd = l >> 3;
    float v = lrelu(a_src[s * 8 + hd] + a_dst[d * 8 + hd]);
    float alpha = __expf(v - dec_f(m1[d * 8 + hd])) / d1[d * 8 + hd];
    int c = l * 4;
    float4 hv = *(const float4*)(h1 + (size_t)s * HID + c);
    float* o = out + (size_t)d * HID + c;
    atomicAdd(o + 0, alpha * hv.x);
    atomicAdd(o + 1, alpha * hv.y);
    atomicAdd(o + 2, alpha * hv.z);
    atomicAdd(o + 3, alpha * hv.w);
}

// ============ bias + ELU (in place) ============
__global__ __launch_bounds__(256) void bias_elu_kernel(
        float* __restrict__ hx, const float* __restrict__ b1) {
    int t = blockIdx.x * 256 + threadIdx.x;
    if (t >= N_NODES * HID) return;
    float v = hx[t] + b1[t & (HID - 1)];
    hx[t] = v > 0.f ? v : expm1f(v);
}

// ============ layer 2 GEMM (wave per node) + attention logits ============
__global__ __launch_bounds__(256) void gemm2_kernel(
        const float* __restrict__ hx, const float* __restrict__ W2,
        const float* __restrict__ as2, const float* __restrict__ ad2,
        float* __restrict__ h2, float* __restrict__ a2s, float* __restrict__ a2d) {
    int t = blockIdx.x * 256 + threadIdx.x;
    int n = t >> 6, l = t & 63;
    if (n >= N_NODES) return;
    float4 xv = *(const float4*)(hx + (size_t)n * HID + l * 4);
    const float* w = W2 + l * 8;          // rows k=4l..4l+3, 2 cols each
    float4 w0 = *(const float4*)(w);
    float4 w1 = *(const float4*)(w + 4);
    float acc0 = xv.x * w0.x + xv.y * w0.z + xv.z * w1.x + xv.w * w1.z;
    float acc1 = xv.x * w0.y + xv.y * w0.w + xv.z * w1.y + xv.w * w1.w;
    #pragma unroll
    for (int off = 32; off; off >>= 1) {
        acc0 += __shfl_down(acc0, off);
        acc1 += __shfl_down(acc1, off);
    }
    if (l == 0) {
        h2[n * 2]     = acc0;
        h2[n * 2 + 1] = acc1;
        a2s[n] = acc0 * as2[0] + acc1 * as2[1];
        a2d[n] = acc0 * ad2[0] + acc1 * ad2[1];
    }
}

// ============ edge passes layer 2 (1 head) ============
__global__ __launch_bounds__(256) void edge_max2_kernel(
        const int* __restrict__ src, const int* __restrict__ dst,
        const float* __restrict__ a2s, const float* __restrict__ a2d,
        unsigned* __restrict__ m2) {
    int e = blockIdx.x * 256 + threadIdx.x;
    if (e >= ET) return;
    int s, d;
    if (e < N_EDGES) { s = src[e]; d = dst[e]; } else { s = d = e - N_EDGES; }
    atomicMax(m2 + d, enc_f(lrelu(a2s[s] + a2d[d])));
}

__global__ __launch_bounds__(256) void edge_sum2_kernel(
        const int* __restrict__ src, const int* __restrict__ dst,
        const float* __restrict__ a2s, const float* __restrict__ a2d,
        const unsigned* __restrict__ m2, float* __restrict__ d2) {
    int e = blockIdx.x * 256 + threadIdx.x;
    if (e >= ET) return;
    int s, d;
    if (e < N_EDGES) { s = src[e]; d = dst[e]; } else { s = d = e - N_EDGES; }
    float v = lrelu(a2s[s] + a2d[d]);
    atomicAdd(d2 + d, __expf(v - dec_f(m2[d])));
}

// ============ seed output with bias2 ============
__global__ __launch_bounds__(256) void out_init_kernel(
        float* __restrict__ out, const float* __restrict__ b2) {
    int t = blockIdx.x * 256 + threadIdx.x;
    if (t >= N_NODES * OUT_C) return;
    out[t] = b2[t & 1];
}

// ============ aggregation layer 2 ============
__global__ __launch_bounds__(256) void agg2_kernel(
        const int* __restrict__ src, const int* __restrict__ dst,
        const float* __restrict__ a2s, const float* __restrict__ a2d,
        const unsigned* __restrict__ m2, const float* __restrict__ d2,
        const float* __restrict__ h2, float* __restrict__ out) {
    int e = blockIdx.x * 256 + threadIdx.x;
    if (e >= ET) return;
    int s, d;
    if (e < N_EDGES) { s = src[e]; d = dst[e]; } else { s = d = e - N_EDGES; }
    float v = lrelu(a2s[s] + a2d[d]);
    float alpha = __expf(v - dec_f(m2[d])) / d2[d];
    atomicAdd(out + d * 2,     alpha * h2[s * 2]);
    atomicAdd(out + d * 2 + 1, alpha * h2[s * 2 + 1]);
}

extern "C" void kernel_launch(void* const* d_in, const int* in_sizes, int n_in,
                              void* d_out, int out_size, void* d_ws, size_t ws_size,
                              hipStream_t stream) {
    (void)in_sizes; (void)n_in; (void)out_size; (void)ws_size;
    const float* x        = (const float*)d_in[0];
    const int*   ei       = (const int*)d_in[1];
    const float* W1       = (const float*)d_in[2];
    const float* att_src1 = (const float*)d_in[3];
    const float* att_dst1 = (const float*)d_in[4];
    const float* b1       = (const float*)d_in[5];
    const float* W2       = (const float*)d_in[6];
    const float* att_src2 = (const float*)d_in[7];
    const float* att_dst2 = (const float*)d_in[8];
    const float* b2       = (const float*)d_in[9];
    float* out = (float*)d_out;

    const int* src = ei;
    const int* dst = ei + N_EDGES;

    // ---- workspace carve-up (bytes) ----
    char* ws = (char*)d_ws;
    size_t off = 0;
    float* h1  = (float*)(ws + off); off += (size_t)N_NODES * HID * 4;     // 51.2 MB
    float* hx  = (float*)(ws + off); off += (size_t)N_NODES * HID * 4;     // 51.2 MB
    float* a_src1 = (float*)(ws + off); off += (size_t)N_NODES * HEADS * 4;
    float* a_dst1 = (float*)(ws + off); off += (size_t)N_NODES * HEADS * 4;
    unsigned* m1  = (unsigned*)(ws + off); off += (size_t)N_NODES * HEADS * 4;
    float* d1     = (float*)(ws + off); off += (size_t)N_NODES * HEADS * 4;
    float* h2  = (float*)(ws + off); off += (size_t)N_NODES * OUT_C * 4;
    float* a2s = (float*)(ws + off); off += (size_t)N_NODES * 4;
    float* a2d = (float*)(ws + off); off += (size_t)N_NODES * 4;
    unsigned* m2 = (unsigned*)(ws + off); off += (size_t)N_NODES * 4;
    float* d2    = (float*)(ws + off); off += (size_t)N_NODES * 4;

    // ---- zero/ident inits (ws is poisoned 0xAA before every call) ----
    hipMemsetAsync(hx, 0, (size_t)N_NODES * HID * 4, stream);
    hipMemsetAsync(m1, 0, (size_t)N_NODES * HEADS * 4, stream);  // enc 0 == -inf identity
    hipMemsetAsync(d1, 0, (size_t)N_NODES * HEADS * 4, stream);
    hipMemsetAsync(m2, 0, (size_t)N_NODES * 4, stream);
    hipMemsetAsync(d2, 0, (size_t)N_NODES * 4, stream);

    const int EB = (ET + 255) / 256;

    // ---- layer 1 ----
    gemm1_kernel<<<dim3((N_NODES + 31) / 32, 4), 256, 0, stream>>>(x, W1, h1);
    att1_kernel<<<(N_NODES * HEADS + 255) / 256, 256, 0, stream>>>(
        h1, att_src1, att_dst1, a_src1, a_dst1);
    edge_max1_kernel<<<EB, 256, 0, stream>>>(src, dst, a_src1, a_dst1, m1);
    edge_sum1_kernel<<<EB, 256, 0, stream>>>(src, dst, a_src1, a_dst1, m1, d1);
    {
        long long tot = (long long)ET * 64;
        int blocks = (int)((tot + 255) / 256);
        agg1_kernel<<<blocks, 256, 0, stream>>>(src, dst, a_src1, a_dst1, m1, d1, h1, hx);
    }
    bias_elu_kernel<<<(N_NODES * HID + 255) / 256, 256, 0, stream>>>(hx, b1);

    // ---- layer 2 ----
    gemm2_kernel<<<(N_NODES * 64 + 255) / 256, 256, 0, stream>>>(
        hx, W2, att_src2, att_dst2, h2, a2s, a2d);
    edge_max2_kernel<<<EB, 256, 0, stream>>>(src, dst, a2s, a2d, m2);
    edge_sum2_kernel<<<EB, 256, 0, stream>>>(src, dst, a2s, a2d, m2, d2);
    out_init_kernel<<<(N_NODES * OUT_C + 255) / 256, 256, 0, stream>>>(out, b2);
    agg2_kernel<<<EB, 256, 0, stream>>>(src, dst, a2s, a2d, m2, d2, h2, out);
}

// Round 2
// 933.552 us; speedup vs baseline: 7.9134x; 7.9134x over previous
//
#include <hip/hip_runtime.h>
#include <hip/hip_bf16.h>
#include <math.h>

#define N_NODES 50000
#define N_EDGES 1600000
#define ET (N_EDGES + N_NODES)   // with self loops
#define IN_C 165
#define HID 256
#define HEADS 8
#define C1 32
#define OUT_C 2
#define NEG_SLOPE 0.2f

__device__ inline float lrelu(float v) { return v > 0.f ? v : NEG_SLOPE * v; }

// ============ Layer 1 GEMM: h1[N,256] = x[N,165] @ W1[165,256] ============
__global__ __launch_bounds__(256) void gemm1_kernel(
        const float* __restrict__ x, const float* __restrict__ W,
        float* __restrict__ h) {
    __shared__ float xs[32 * IN_C];
    const int row0 = blockIdx.x * 32;
    const int colb = blockIdx.y * 64;
    const int tid = threadIdx.x;
    for (int idx = tid; idx < 32 * IN_C; idx += 256) {
        int r = idx / IN_C, c = idx - r * IN_C;
        int gr = row0 + r;
        xs[idx] = (gr < N_NODES) ? x[gr * IN_C + c] : 0.f;
    }
    __syncthreads();
    const int r = tid & 31;
    const int cg = tid >> 5;           // 0..7
    const int c0 = colb + cg * 8;
    float acc[8] = {0.f, 0.f, 0.f, 0.f, 0.f, 0.f, 0.f, 0.f};
    for (int k = 0; k < IN_C; ++k) {
        float xv = xs[r * IN_C + k];
        const float* w = W + k * HID + c0;
        float4 w0 = *(const float4*)(w);
        float4 w1 = *(const float4*)(w + 4);
        acc[0] += xv * w0.x; acc[1] += xv * w0.y;
        acc[2] += xv * w0.z; acc[3] += xv * w0.w;
        acc[4] += xv * w1.x; acc[5] += xv * w1.y;
        acc[6] += xv * w1.z; acc[7] += xv * w1.w;
    }
    int gr = row0 + r;
    if (gr < N_NODES) {
        float* o = h + gr * HID + c0;
        *(float4*)(o)     = make_float4(acc[0], acc[1], acc[2], acc[3]);
        *(float4*)(o + 4) = make_float4(acc[4], acc[5], acc[6], acc[7]);
    }
}

// ============ per-node attention logits, layer 1 ============
__global__ __launch_bounds__(256) void att1_kernel(
        const float* __restrict__ h, const float* __restrict__ att_src,
        const float* __restrict__ att_dst,
        float* __restrict__ a_src, float* __restrict__ a_dst) {
    int t = blockIdx.x * 256 + threadIdx.x;   // t = n*8 + head
    if (t >= N_NODES * HEADS) return;
    int hd = t & 7;
    const float* hp = h + (size_t)t * C1;     // n*256 + hd*32 == t*32
    const float* as = att_src + hd * C1;
    const float* ad = att_dst + hd * C1;
    float s = 0.f, d = 0.f;
    for (int c = 0; c < C1; c += 4) {
        float4 hv = *(const float4*)(hp + c);
        float4 av = *(const float4*)(as + c);
        float4 dv = *(const float4*)(ad + c);
        s += hv.x * av.x + hv.y * av.y + hv.z * av.z + hv.w * av.w;
        d += hv.x * dv.x + hv.y * dv.y + hv.z * dv.z + hv.w * dv.w;
    }
    a_src[t] = s;
    a_dst[t] = d;
}

// ============ CSR build: histogram of dst ============
__global__ __launch_bounds__(256) void hist_kernel(
        const int* __restrict__ dst, int* __restrict__ deg) {
    int e = blockIdx.x * 256 + threadIdx.x;
    if (e >= ET) return;
    int d = (e < N_EDGES) ? dst[e] : e - N_EDGES;
    atomicAdd(&deg[d], 1);
}

// ============ CSR build: single-block exclusive scan -> rowptr[N+1] ============
__global__ __launch_bounds__(1024) void scan_kernel(
        const int* __restrict__ deg, int* __restrict__ rowptr) {
    __shared__ int buf[1024];
    __shared__ int carry_s;
    const int tid = threadIdx.x;
    if (tid == 0) { carry_s = 0; rowptr[0] = 0; }
    __syncthreads();
    for (int base = 0; base < N_NODES; base += 1024) {
        int i = base + tid;
        buf[tid] = (i < N_NODES) ? deg[i] : 0;
        __syncthreads();
        for (int off = 1; off < 1024; off <<= 1) {
            int t = (tid >= off) ? buf[tid - off] : 0;
            __syncthreads();
            buf[tid] += t;
            __syncthreads();
        }
        int c = carry_s;
        if (i < N_NODES) rowptr[i + 1] = c + buf[tid];
        __syncthreads();
        if (tid == 0) carry_s = c + buf[1023];
        __syncthreads();
    }
}

// ============ CSR build: scatter src ids into dst buckets ============
__global__ __launch_bounds__(256) void scatter_kernel(
        const int* __restrict__ src, const int* __restrict__ dst,
        int* __restrict__ cursor, int* __restrict__ csr_src) {
    int e = blockIdx.x * 256 + threadIdx.x;
    if (e >= ET) return;
    int s, d;
    if (e < N_EDGES) { s = src[e]; d = dst[e]; } else { s = d = e - N_EDGES; }
    int pos = atomicAdd(&cursor[d], 1);
    csr_src[pos] = s;
}

// ============ Layer 1 fused: softmax + gather-aggregate + bias + ELU ============
// one wave per dst node; no atomics.
__global__ __launch_bounds__(256) void agg1_fused_kernel(
        const int* __restrict__ rowptr, const int* __restrict__ csr_src,
        const float* __restrict__ a_src, const float* __restrict__ a_dst,
        const float* __restrict__ h1, const float* __restrict__ b1,
        float* __restrict__ hx) {
    int wid = (blockIdx.x * 256 + threadIdx.x) >> 6;   // node
    int l = threadIdx.x & 63;
    if (wid >= N_NODES) return;
    const int start = rowptr[wid];
    const int deg = rowptr[wid + 1] - start;

    // --- pass 1: per-head max & denom. lane = slot*8 + head ---
    const int h = l & 7;
    const float ad_h = a_dst[wid * 8 + h];
    float mx = -1e30f;
    for (int i = (l >> 3); i < deg; i += 8) {
        int s = csr_src[start + i];
        mx = fmaxf(mx, lrelu(a_src[s * 8 + h] + ad_h));
    }
    mx = fmaxf(mx, __shfl_xor(mx, 8));
    mx = fmaxf(mx, __shfl_xor(mx, 16));
    mx = fmaxf(mx, __shfl_xor(mx, 32));
    float sm = 0.f;
    for (int i = (l >> 3); i < deg; i += 8) {
        int s = csr_src[start + i];
        sm += __expf(lrelu(a_src[s * 8 + h] + ad_h) - mx);
    }
    sm += __shfl_xor(sm, 8);
    sm += __shfl_xor(sm, 16);
    sm += __shfl_xor(sm, 32);

    // --- pass 2: weighted gather. lane owns channels l*4..l*4+3, head l>>3 ---
    const int hp = l >> 3;
    const float m_p  = __shfl(mx, hp);     // lane hp holds head hp's max
    const float den  = __shfl(sm, hp);
    const float ad_p = a_dst[wid * 8 + hp];
    float4 acc = make_float4(0.f, 0.f, 0.f, 0.f);
    for (int i = 0; i < deg; ++i) {
        int s = csr_src[start + i];
        float alpha = __expf(lrelu(a_src[s * 8 + hp] + ad_p) - m_p) / den;
        float4 hv = *(const float4*)(h1 + (size_t)s * HID + l * 4);
        acc.x += alpha * hv.x; acc.y += alpha * hv.y;
        acc.z += alpha * hv.z; acc.w += alpha * hv.w;
    }
    float4 bv = *(const float4*)(b1 + l * 4);
    float o0 = acc.x + bv.x, o1 = acc.y + bv.y;
    float o2 = acc.z + bv.z, o3 = acc.w + bv.w;
    o0 = o0 > 0.f ? o0 : expm1f(o0);
    o1 = o1 > 0.f ? o1 : expm1f(o1);
    o2 = o2 > 0.f ? o2 : expm1f(o2);
    o3 = o3 > 0.f ? o3 : expm1f(o3);
    *(float4*)(hx + (size_t)wid * HID + l * 4) = make_float4(o0, o1, o2, o3);
}

// ============ layer 2 GEMM (wave per node) + attention logits ============
__global__ __launch_bounds__(256) void gemm2_kernel(
        const float* __restrict__ hx, const float* __restrict__ W2,
        const float* __restrict__ as2, const float* __restrict__ ad2,
        float* __restrict__ h2, float* __restrict__ a2s, float* __restrict__ a2d) {
    int t = blockIdx.x * 256 + threadIdx.x;
    int n = t >> 6, l = t & 63;
    if (n >= N_NODES) return;
    float4 xv = *(const float4*)(hx + (size_t)n * HID + l * 4);
    const float* w = W2 + l * 8;          // rows k=4l..4l+3, 2 cols each
    float4 w0 = *(const float4*)(w);
    float4 w1 = *(const float4*)(w + 4);
    float acc0 = xv.x * w0.x + xv.y * w0.z + xv.z * w1.x + xv.w * w1.z;
    float acc1 = xv.x * w0.y + xv.y * w0.w + xv.z * w1.y + xv.w * w1.w;
    #pragma unroll
    for (int off = 32; off; off >>= 1) {
        acc0 += __shfl_down(acc0, off);
        acc1 += __shfl_down(acc1, off);
    }
    if (l == 0) {
        h2[n * 2]     = acc0;
        h2[n * 2 + 1] = acc1;
        a2s[n] = acc0 * as2[0] + acc1 * as2[1];
        a2d[n] = acc0 * ad2[0] + acc1 * ad2[1];
    }
}

// ============ Layer 2 fused: softmax + aggregate + bias, wave per node ============
__global__ __launch_bounds__(256) void agg2_fused_kernel(
        const int* __restrict__ rowptr, const int* __restrict__ csr_src,
        const float* __restrict__ a2s, const float* __restrict__ a2d,
        const float* __restrict__ h2, const float* __restrict__ b2,
        float* __restrict__ out) {
    int wid = (blockIdx.x * 256 + threadIdx.x) >> 6;
    int l = threadIdx.x & 63;
    if (wid >= N_NODES) return;
    const int start = rowptr[wid];
    const int deg = rowptr[wid + 1] - start;
    const float adv = a2d[wid];
    float mx = -1e30f;
    for (int i = l; i < deg; i += 64) {
        int s = csr_src[start + i];
        mx = fmaxf(mx, lrelu(a2s[s] + adv));
    }
    #pragma unroll
    for (int off = 32; off; off >>= 1) mx = fmaxf(mx, __shfl_xor(mx, off));
    float sm = 0.f, acc0 = 0.f, acc1 = 0.f;
    for (int i = l; i < deg; i += 64) {
        int s = csr_src[start + i];
        float au = __expf(lrelu(a2s[s] + adv) - mx);
        sm += au;
        acc0 += au * h2[s * 2];
        acc1 += au * h2[s * 2 + 1];
    }
    #pragma unroll
    for (int off = 32; off; off >>= 1) {
        sm   += __shfl_xor(sm, off);
        acc0 += __shfl_xor(acc0, off);
        acc1 += __shfl_xor(acc1, off);
    }
    if (l == 0) {
        out[wid * 2]     = acc0 / sm + b2[0];
        out[wid * 2 + 1] = acc1 / sm + b2[1];
    }
}

extern "C" void kernel_launch(void* const* d_in, const int* in_sizes, int n_in,
                              void* d_out, int out_size, void* d_ws, size_t ws_size,
                              hipStream_t stream) {
    (void)in_sizes; (void)n_in; (void)out_size; (void)ws_size;
    const float* x        = (const float*)d_in[0];
    const int*   ei       = (const int*)d_in[1];
    const float* W1       = (const float*)d_in[2];
    const float* att_src1 = (const float*)d_in[3];
    const float* att_dst1 = (const float*)d_in[4];
    const float* b1       = (const float*)d_in[5];
    const float* W2       = (const float*)d_in[6];
    const float* att_src2 = (const float*)d_in[7];
    const float* att_dst2 = (const float*)d_in[8];
    const float* b2       = (const float*)d_in[9];
    float* out = (float*)d_out;

    const int* src = ei;
    const int* dst = ei + N_EDGES;

    // ---- workspace carve-up (bytes) ----
    char* ws = (char*)d_ws;
    size_t off = 0;
    float* h1  = (float*)(ws + off); off += (size_t)N_NODES * HID * 4;     // 51.2 MB
    float* hx  = (float*)(ws + off); off += (size_t)N_NODES * HID * 4;     // 51.2 MB
    float* a_src1 = (float*)(ws + off); off += (size_t)N_NODES * HEADS * 4;
    float* a_dst1 = (float*)(ws + off); off += (size_t)N_NODES * HEADS * 4;
    float* h2  = (float*)(ws + off); off += (size_t)N_NODES * OUT_C * 4;
    float* a2s = (float*)(ws + off); off += (size_t)N_NODES * 4;
    float* a2d = (float*)(ws + off); off += (size_t)N_NODES * 4;
    int* deg    = (int*)(ws + off); off += (size_t)N_NODES * 4;
    int* rowptr = (int*)(ws + off); off += (size_t)(N_NODES + 1) * 4;
    int* cursor = (int*)(ws + off); off += (size_t)N_NODES * 4;
    int* csr_src = (int*)(ws + off); off += (size_t)ET * 4;                // 6.6 MB

    hipMemsetAsync(deg, 0, (size_t)N_NODES * 4, stream);

    const int EB = (ET + 255) / 256;
    const int NW = (N_NODES * 64 + 255) / 256;   // wave-per-node grids

    // ---- CSR build (dst-sorted) ----
    hist_kernel<<<EB, 256, 0, stream>>>(dst, deg);
    scan_kernel<<<1, 1024, 0, stream>>>(deg, rowptr);
    hipMemcpyAsync(cursor, rowptr, (size_t)N_NODES * 4, hipMemcpyDeviceToDevice, stream);
    scatter_kernel<<<EB, 256, 0, stream>>>(src, dst, cursor, csr_src);

    // ---- layer 1 ----
    gemm1_kernel<<<dim3((N_NODES + 31) / 32, 4), 256, 0, stream>>>(x, W1, h1);
    att1_kernel<<<(N_NODES * HEADS + 255) / 256, 256, 0, stream>>>(
        h1, att_src1, att_dst1, a_src1, a_dst1);
    agg1_fused_kernel<<<NW, 256, 0, stream>>>(
        rowptr, csr_src, a_src1, a_dst1, h1, b1, hx);

    // ---- layer 2 ----
    gemm2_kernel<<<NW, 256, 0, stream>>>(hx, W2, att_src2, att_dst2, h2, a2s, a2d);
    agg2_fused_kernel<<<NW, 256, 0, stream>>>(rowptr, csr_src, a2s, a2d, h2, b2, out);
}

// Round 3
// 727.404 us; speedup vs baseline: 10.1561x; 1.2834x over previous
//
#include <hip/hip_runtime.h>
#include <hip/hip_bf16.h>
#include <math.h>

#define N_NODES 50000
#define N_EDGES 1600000
#define ET (N_EDGES + N_NODES)   // with self loops
#define IN_C 165
#define HID 256
#define HEADS 8
#define C1 32
#define OUT_C 2
#define NEG_SLOPE 0.2f

__device__ inline float lrelu(float v) { return v > 0.f ? v : NEG_SLOPE * v; }

// ============ Layer 1 GEMM: h1[N,256] = x[N,165] @ W1[165,256] ============
// 64 rows x 256 cols per block; thread = 4 rows x 16 cols (64 FMA per k).
__global__ __launch_bounds__(256) void gemm1_kernel(
        const float* __restrict__ x, const float* __restrict__ W,
        float* __restrict__ h) {
    __shared__ float xs[64 * IN_C];           // 42.2 KB
    const int row0 = blockIdx.x * 64;
    const int tid = threadIdx.x;
    const int nrow = (N_NODES - row0 < 64) ? (N_NODES - row0) : 64;
    const int lim = nrow * IN_C;
    for (int idx = tid; idx < 64 * IN_C; idx += 256)
        xs[idx] = (idx < lim) ? x[(size_t)row0 * IN_C + idx] : 0.f;
    __syncthreads();
    const int tr = tid & 15;                  // 16 row-groups of 4
    const int c0 = (tid >> 4) * 16;           // 16 col-groups of 16
    float acc[4][16];
    #pragma unroll
    for (int j = 0; j < 4; ++j)
        #pragma unroll
        for (int q = 0; q < 16; ++q) acc[j][q] = 0.f;
    const float* xb = xs + (tr * 4) * IN_C;
    for (int k = 0; k < IN_C; ++k) {
        float xv0 = xb[k];
        float xv1 = xb[IN_C + k];
        float xv2 = xb[2 * IN_C + k];
        float xv3 = xb[3 * IN_C + k];
        const float* wp = W + k * HID + c0;
        #pragma unroll
        for (int q = 0; q < 4; ++q) {
            float4 wq = *(const float4*)(wp + q * 4);
            acc[0][q*4+0] += xv0 * wq.x; acc[0][q*4+1] += xv0 * wq.y;
            acc[0][q*4+2] += xv0 * wq.z; acc[0][q*4+3] += xv0 * wq.w;
            acc[1][q*4+0] += xv1 * wq.x; acc[1][q*4+1] += xv1 * wq.y;
            acc[1][q*4+2] += xv1 * wq.z; acc[1][q*4+3] += xv1 * wq.w;
            acc[2][q*4+0] += xv2 * wq.x; acc[2][q*4+1] += xv2 * wq.y;
            acc[2][q*4+2] += xv2 * wq.z; acc[2][q*4+3] += xv2 * wq.w;
            acc[3][q*4+0] += xv3 * wq.x; acc[3][q*4+1] += xv3 * wq.y;
            acc[3][q*4+2] += xv3 * wq.z; acc[3][q*4+3] += xv3 * wq.w;
        }
    }
    #pragma unroll
    for (int j = 0; j < 4; ++j) {
        int gr = row0 + tr * 4 + j;
        if (gr < N_NODES) {
            float* o = h + (size_t)gr * HID + c0;
            #pragma unroll
            for (int q = 0; q < 4; ++q)
                *(float4*)(o + q * 4) = make_float4(acc[j][q*4+0], acc[j][q*4+1],
                                                    acc[j][q*4+2], acc[j][q*4+3]);
        }
    }
}

// ============ per-node attention logits, layer 1 ============
__global__ __launch_bounds__(256) void att1_kernel(
        const float* __restrict__ h, const float* __restrict__ att_src,
        const float* __restrict__ att_dst,
        float* __restrict__ a_src, float* __restrict__ a_dst) {
    int t = blockIdx.x * 256 + threadIdx.x;   // t = n*8 + head
    if (t >= N_NODES * HEADS) return;
    int hd = t & 7;
    const float* hp = h + (size_t)t * C1;     // n*256 + hd*32 == t*32
    const float* as = att_src + hd * C1;
    const float* ad = att_dst + hd * C1;
    float s = 0.f, d = 0.f;
    for (int c = 0; c < C1; c += 4) {
        float4 hv = *(const float4*)(hp + c);
        float4 av = *(const float4*)(as + c);
        float4 dv = *(const float4*)(ad + c);
        s += hv.x * av.x + hv.y * av.y + hv.z * av.z + hv.w * av.w;
        d += hv.x * dv.x + hv.y * dv.y + hv.z * dv.z + hv.w * dv.w;
    }
    a_src[t] = s;
    a_dst[t] = d;
}

// ============ CSR build: histogram of dst ============
__global__ __launch_bounds__(256) void hist_kernel(
        const int* __restrict__ dst, int* __restrict__ deg) {
    int e = blockIdx.x * 256 + threadIdx.x;
    if (e >= ET) return;
    int d = (e < N_EDGES) ? dst[e] : e - N_EDGES;
    atomicAdd(&deg[d], 1);
}

// ============ CSR scan, stage A: per-block (1024) inclusive scan ============
__global__ __launch_bounds__(1024) void scanA_kernel(
        const int* __restrict__ deg, int* __restrict__ tmp, int* __restrict__ bs) {
    const int i = blockIdx.x * 1024 + threadIdx.x;
    const int l = threadIdx.x & 63;
    const int w = threadIdx.x >> 6;           // 16 waves
    int v = (i < N_NODES) ? deg[i] : 0;
    int sc = v;
    #pragma unroll
    for (int off = 1; off < 64; off <<= 1) {
        int t = __shfl_up(sc, off);
        if (l >= off) sc += t;
    }
    __shared__ int ws[16];
    if (l == 63) ws[w] = sc;
    __syncthreads();
    if (threadIdx.x < 16) {
        int t = ws[threadIdx.x];
        #pragma unroll
        for (int off = 1; off < 16; off <<= 1) {
            int u = __shfl_up(t, off);
            if ((int)threadIdx.x >= off) t += u;
        }
        ws[threadIdx.x] = t;                  // inclusive wave sums
    }
    __syncthreads();
    int incl = sc + (w > 0 ? ws[w - 1] : 0);
    if (i < N_NODES) tmp[i] = incl;
    if (threadIdx.x == 1023) bs[blockIdx.x] = incl;
}

// ============ CSR scan, stage B: scan 49 block sums (1 wave) ============
__global__ __launch_bounds__(64) void scanB_kernel(
        const int* __restrict__ bs, int* __restrict__ boff) {
    const int l = threadIdx.x;
    int v = (l < 49) ? bs[l] : 0;
    int sc = v;
    #pragma unroll
    for (int off = 1; off < 64; off <<= 1) {
        int t = __shfl_up(sc, off);
        if (l >= off) sc += t;
    }
    if (l < 49) boff[l] = sc - v;             // exclusive
}

// ============ CSR scan, stage C: finalize rowptr + cursor ============
__global__ __launch_bounds__(256) void scanC_kernel(
        const int* __restrict__ tmp, const int* __restrict__ boff,
        const int* __restrict__ deg, int* __restrict__ rowptr,
        int* __restrict__ cursor) {
    int i = blockIdx.x * 256 + threadIdx.x;
    if (i >= N_NODES) return;
    int incl = tmp[i] + boff[i >> 10];
    rowptr[i + 1] = incl;
    cursor[i] = incl - deg[i];
    if (i == 0) rowptr[0] = 0;
}

// ============ CSR build: scatter src ids into dst buckets ============
__global__ __launch_bounds__(256) void scatter_kernel(
        const int* __restrict__ src, const int* __restrict__ dst,
        int* __restrict__ cursor, int* __restrict__ csr_src) {
    int e = blockIdx.x * 256 + threadIdx.x;
    if (e >= ET) return;
    int s, d;
    if (e < N_EDGES) { s = src[e]; d = dst[e]; } else { s = d = e - N_EDGES; }
    int pos = atomicAdd(&cursor[d], 1);
    csr_src[pos] = s;
}

// ============ Layer 1 fused: single-pass softmax-aggregate + bias + ELU ======
// One wave per dst node, no max pass (softmax shift-invariance), no atomics.
// Lane l: head hp=l>>3, channels l*4..l*4+3 (channel block belongs to head hp).
// All 8 lanes of a head compute the identical denominator -> no reduction.
__global__ __launch_bounds__(256) void agg1_fused_kernel(
        const int* __restrict__ rowptr, const int* __restrict__ csr_src,
        const float* __restrict__ a_src, const float* __restrict__ a_dst,
        const float* __restrict__ h1, const float* __restrict__ b1,
        float* __restrict__ hx) {
    int wid = (blockIdx.x * 256 + threadIdx.x) >> 6;
    int l = threadIdx.x & 63;
    if (wid >= N_NODES) return;
    int i = rowptr[wid];
    const int end = rowptr[wid + 1];
    const int hp = l >> 3;
    const float ad_p = a_dst[wid * 8 + hp];
    const int c = l * 4;
    float den = 0.f;
    float ax = 0.f, ay = 0.f, az = 0.f, aw = 0.f;
    for (; i + 4 <= end; i += 4) {
        int s0 = csr_src[i + 0], s1 = csr_src[i + 1];
        int s2 = csr_src[i + 2], s3 = csr_src[i + 3];
        float4 v0 = *(const float4*)(h1 + (size_t)s0 * HID + c);
        float4 v1 = *(const float4*)(h1 + (size_t)s1 * HID + c);
        float4 v2 = *(const float4*)(h1 + (size_t)s2 * HID + c);
        float4 v3 = *(const float4*)(h1 + (size_t)s3 * HID + c);
        float w0 = __expf(lrelu(a_src[s0 * 8 + hp] + ad_p));
        float w1 = __expf(lrelu(a_src[s1 * 8 + hp] + ad_p));
        float w2 = __expf(lrelu(a_src[s2 * 8 + hp] + ad_p));
        float w3 = __expf(lrelu(a_src[s3 * 8 + hp] + ad_p));
        den += (w0 + w1) + (w2 + w3);
        ax += w0 * v0.x + w1 * v1.x + w2 * v2.x + w3 * v3.x;
        ay += w0 * v0.y + w1 * v1.y + w2 * v2.y + w3 * v3.y;
        az += w0 * v0.z + w1 * v1.z + w2 * v2.z + w3 * v3.z;
        aw += w0 * v0.w + w1 * v1.w + w2 * v2.w + w3 * v3.w;
    }
    for (; i < end; ++i) {
        int s = csr_src[i];
        float4 v = *(const float4*)(h1 + (size_t)s * HID + c);
        float w = __expf(lrelu(a_src[s * 8 + hp] + ad_p));
        den += w;
        ax += w * v.x; ay += w * v.y; az += w * v.z; aw += w * v.w;
    }
    const float inv = 1.f / den;
    float4 bv = *(const float4*)(b1 + c);
    float o0 = ax * inv + bv.x, o1 = ay * inv + bv.y;
    float o2 = az * inv + bv.z, o3 = aw * inv + bv.w;
    o0 = o0 > 0.f ? o0 : expm1f(o0);
    o1 = o1 > 0.f ? o1 : expm1f(o1);
    o2 = o2 > 0.f ? o2 : expm1f(o2);
    o3 = o3 > 0.f ? o3 : expm1f(o3);
    *(float4*)(hx + (size_t)wid * HID + c) = make_float4(o0, o1, o2, o3);
}

// ============ layer 2 GEMM (wave per node) + attention logits ============
__global__ __launch_bounds__(256) void gemm2_kernel(
        const float* __restrict__ hx, const float* __restrict__ W2,
        const float* __restrict__ as2, const float* __restrict__ ad2,
        float* __restrict__ h2, float* __restrict__ a2s, float* __restrict__ a2d) {
    int t = blockIdx.x * 256 + threadIdx.x;
    int n = t >> 6, l = t & 63;
    if (n >= N_NODES) return;
    float4 xv = *(const float4*)(hx + (size_t)n * HID + l * 4);
    const float* w = W2 + l * 8;          // rows k=4l..4l+3, 2 cols each
    float4 w0 = *(const float4*)(w);
    float4 w1 = *(const float4*)(w + 4);
    float acc0 = xv.x * w0.x + xv.y * w0.z + xv.z * w1.x + xv.w * w1.z;
    float acc1 = xv.x * w0.y + xv.y * w0.w + xv.z * w1.y + xv.w * w1.w;
    #pragma unroll
    for (int off = 32; off; off >>= 1) {
        acc0 += __shfl_down(acc0, off);
        acc1 += __shfl_down(acc1, off);
    }
    if (l == 0) {
        h2[n * 2]     = acc0;
        h2[n * 2 + 1] = acc1;
        a2s[n] = acc0 * as2[0] + acc1 * as2[1];
        a2d[n] = acc0 * ad2[0] + acc1 * ad2[1];
    }
}

// ============ Layer 2 fused: single-pass softmax-aggregate + bias ============
__global__ __launch_bounds__(256) void agg2_fused_kernel(
        const int* __restrict__ rowptr, const int* __restrict__ csr_src,
        const float* __restrict__ a2s, const float* __restrict__ a2d,
        const float* __restrict__ h2, const float* __restrict__ b2,
        float* __restrict__ out) {
    int wid = (blockIdx.x * 256 + threadIdx.x) >> 6;
    int l = threadIdx.x & 63;
    if (wid >= N_NODES) return;
    const int start = rowptr[wid];
    const int end = rowptr[wid + 1];
    const float adv = a2d[wid];
    float sm = 0.f, acc0 = 0.f, acc1 = 0.f;
    for (int i = start + l; i < end; i += 64) {
        int s = csr_src[i];
        float w = __expf(lrelu(a2s[s] + adv));
        sm += w;
        acc0 += w * h2[s * 2];
        acc1 += w * h2[s * 2 + 1];
    }
    #pragma unroll
    for (int off = 32; off; off >>= 1) {
        sm   += __shfl_xor(sm, off);
        acc0 += __shfl_xor(acc0, off);
        acc1 += __shfl_xor(acc1, off);
    }
    if (l == 0) {
        out[wid * 2]     = acc0 / sm + b2[0];
        out[wid * 2 + 1] = acc1 / sm + b2[1];
    }
}

extern "C" void kernel_launch(void* const* d_in, const int* in_sizes, int n_in,
                              void* d_out, int out_size, void* d_ws, size_t ws_size,
                              hipStream_t stream) {
    (void)in_sizes; (void)n_in; (void)out_size; (void)ws_size;
    const float* x        = (const float*)d_in[0];
    const int*   ei       = (const int*)d_in[1];
    const float* W1       = (const float*)d_in[2];
    const float* att_src1 = (const float*)d_in[3];
    const float* att_dst1 = (const float*)d_in[4];
    const float* b1       = (const float*)d_in[5];
    const float* W2       = (const float*)d_in[6];
    const float* att_src2 = (const float*)d_in[7];
    const float* att_dst2 = (const float*)d_in[8];
    const float* b2       = (const float*)d_in[9];
    float* out = (float*)d_out;

    const int* src = ei;
    const int* dst = ei + N_EDGES;

    // ---- workspace carve-up (bytes) ----
    char* ws = (char*)d_ws;
    size_t off = 0;
    float* h1  = (float*)(ws + off); off += (size_t)N_NODES * HID * 4;     // 51.2 MB
    float* hx  = (float*)(ws + off); off += (size_t)N_NODES * HID * 4;     // 51.2 MB
    float* a_src1 = (float*)(ws + off); off += (size_t)N_NODES * HEADS * 4;
    float* a_dst1 = (float*)(ws + off); off += (size_t)N_NODES * HEADS * 4;
    float* h2  = (float*)(ws + off); off += (size_t)N_NODES * OUT_C * 4;
    float* a2s = (float*)(ws + off); off += (size_t)N_NODES * 4;
    float* a2d = (float*)(ws + off); off += (size_t)N_NODES * 4;
    int* deg    = (int*)(ws + off); off += (size_t)N_NODES * 4;
    int* rowptr = (int*)(ws + off); off += (size_t)(N_NODES + 1) * 4;
    int* cursor = (int*)(ws + off); off += (size_t)N_NODES * 4;
    int* tmp    = (int*)(ws + off); off += (size_t)N_NODES * 4;
    int* bs     = (int*)(ws + off); off += 64 * 4;
    int* boff   = (int*)(ws + off); off += 64 * 4;
    int* csr_src = (int*)(ws + off); off += (size_t)ET * 4;                // 6.6 MB

    hipMemsetAsync(deg, 0, (size_t)N_NODES * 4, stream);

    const int EB = (ET + 255) / 256;
    const int NW = (N_NODES * 64 + 255) / 256;        // wave-per-node grids
    const int SB = (N_NODES + 1023) / 1024;           // 49 scan blocks

    // ---- CSR build (dst buckets) ----
    hist_kernel<<<EB, 256, 0, stream>>>(dst, deg);
    scanA_kernel<<<SB, 1024, 0, stream>>>(deg, tmp, bs);
    scanB_kernel<<<1, 64, 0, stream>>>(bs, boff);
    scanC_kernel<<<(N_NODES + 255) / 256, 256, 0, stream>>>(tmp, boff, deg, rowptr, cursor);
    scatter_kernel<<<EB, 256, 0, stream>>>(src, dst, cursor, csr_src);

    // ---- layer 1 ----
    gemm1_kernel<<<(N_NODES + 63) / 64, 256, 0, stream>>>(x, W1, h1);
    att1_kernel<<<(N_NODES * HEADS + 255) / 256, 256, 0, stream>>>(
        h1, att_src1, att_dst1, a_src1, a_dst1);
    agg1_fused_kernel<<<NW, 256, 0, stream>>>(
        rowptr, csr_src, a_src1, a_dst1, h1, b1, hx);

    // ---- layer 2 ----
    gemm2_kernel<<<NW, 256, 0, stream>>>(hx, W2, att_src2, att_dst2, h2, a2s, a2d);
    agg2_fused_kernel<<<NW, 256, 0, stream>>>(rowptr, csr_src, a2s, a2d, h2, b2, out);
}

// Round 4
// 705.849 us; speedup vs baseline: 10.4663x; 1.0305x over previous
//
#include <hip/hip_runtime.h>
#include <hip/hip_bf16.h>
#include <math.h>

#define N_NODES 50000
#define N_EDGES 1600000
#define ET (N_EDGES + N_NODES)   // with self loops
#define IN_C 165
#define HID 256
#define HEADS 8
#define C1 32
#define OUT_C 2
#define NEG_SLOPE 0.2f
#define SB ((N_NODES + 1023) / 1024)   // 49 scan blocks

__device__ inline float lrelu(float v) { return v > 0.f ? v : NEG_SLOPE * v; }

// ============ Layer 1 GEMM + fused attention logits ============
// 64 rows x 256 cols per block; thread = 4 rows x 16 cols (64 FMA per k).
// Epilogue computes a_src/a_dst via per-head partial dots reduced in LDS.
__global__ __launch_bounds__(256) void gemm1_att_kernel(
        const float* __restrict__ x, const float* __restrict__ W,
        const float* __restrict__ att_src, const float* __restrict__ att_dst,
        float* __restrict__ h, float* __restrict__ a_src, float* __restrict__ a_dst) {
    __shared__ float xs[64 * IN_C];           // 42.2 KB
    __shared__ float sh_s[64][16];            // 4 KB
    __shared__ float sh_d[64][16];            // 4 KB
    const int row0 = blockIdx.x * 64;
    const int tid = threadIdx.x;
    const int nrow = (N_NODES - row0 < 64) ? (N_NODES - row0) : 64;
    const int lim = nrow * IN_C;
    for (int idx = tid; idx < 64 * IN_C; idx += 256)
        xs[idx] = (idx < lim) ? x[(size_t)row0 * IN_C + idx] : 0.f;
    __syncthreads();
    const int tr = tid & 15;                  // 16 row-groups of 4
    const int cq = tid >> 4;                  // col-group 0..15
    const int c0 = cq * 16;
    float acc[4][16];
    #pragma unroll
    for (int j = 0; j < 4; ++j)
        #pragma unroll
        for (int q = 0; q < 16; ++q) acc[j][q] = 0.f;
    const float* xb = xs + (tr * 4) * IN_C;
    for (int k = 0; k < IN_C; ++k) {
        float xv0 = xb[k];
        float xv1 = xb[IN_C + k];
        float xv2 = xb[2 * IN_C + k];
        float xv3 = xb[3 * IN_C + k];
        const float* wp = W + k * HID + c0;
        #pragma unroll
        for (int q = 0; q < 4; ++q) {
            float4 wq = *(const float4*)(wp + q * 4);
            acc[0][q*4+0] += xv0 * wq.x; acc[0][q*4+1] += xv0 * wq.y;
            acc[0][q*4+2] += xv0 * wq.z; acc[0][q*4+3] += xv0 * wq.w;
            acc[1][q*4+0] += xv1 * wq.x; acc[1][q*4+1] += xv1 * wq.y;
            acc[1][q*4+2] += xv1 * wq.z; acc[1][q*4+3] += xv1 * wq.w;
            acc[2][q*4+0] += xv2 * wq.x; acc[2][q*4+1] += xv2 * wq.y;
            acc[2][q*4+2] += xv2 * wq.z; acc[2][q*4+3] += xv2 * wq.w;
            acc[3][q*4+0] += xv3 * wq.x; acc[3][q*4+1] += xv3 * wq.y;
            acc[3][q*4+2] += xv3 * wq.z; acc[3][q*4+3] += xv3 * wq.w;
        }
    }
    // store h tile
    #pragma unroll
    for (int j = 0; j < 4; ++j) {
        int gr = row0 + tr * 4 + j;
        if (gr < N_NODES) {
            float* o = h + (size_t)gr * HID + c0;
            #pragma unroll
            for (int q = 0; q < 4; ++q)
                *(float4*)(o + q * 4) = make_float4(acc[j][q*4+0], acc[j][q*4+1],
                                                    acc[j][q*4+2], acc[j][q*4+3]);
        }
    }
    // ---- fused attention partial dots ----
    // cols [c0, c0+16) lie in head hd = cq>>1, channel offset (cq&1)*16
    {
        const int hd = cq >> 1;
        const float* as = att_src + hd * C1 + (cq & 1) * 16;
        const float* ad = att_dst + hd * C1 + (cq & 1) * 16;
        float av[16], dv[16];
        #pragma unroll
        for (int q = 0; q < 4; ++q) {
            float4 a4 = *(const float4*)(as + q * 4);
            float4 d4 = *(const float4*)(ad + q * 4);
            av[q*4+0]=a4.x; av[q*4+1]=a4.y; av[q*4+2]=a4.z; av[q*4+3]=a4.w;
            dv[q*4+0]=d4.x; dv[q*4+1]=d4.y; dv[q*4+2]=d4.z; dv[q*4+3]=d4.w;
        }
        #pragma unroll
        for (int j = 0; j < 4; ++j) {
            float ps = 0.f, pd = 0.f;
            #pragma unroll
            for (int q = 0; q < 16; ++q) {
                ps += acc[j][q] * av[q];
                pd += acc[j][q] * dv[q];
            }
            sh_s[tr * 4 + j][cq] = ps;
            sh_d[tr * 4 + j][cq] = pd;
        }
    }
    __syncthreads();
    #pragma unroll
    for (int o = tid; o < 512; o += 256) {    // 2 iters: (row, head) pairs
        int r = o >> 3, hd = o & 7;
        int gr = row0 + r;
        if (gr < N_NODES) {
            a_src[gr * 8 + hd] = sh_s[r][hd * 2] + sh_s[r][hd * 2 + 1];
            a_dst[gr * 8 + hd] = sh_d[r][hd * 2] + sh_d[r][hd * 2 + 1];
        }
    }
}

// ============ CSR build: histogram of dst ============
__global__ __launch_bounds__(256) void hist_kernel(
        const int* __restrict__ dst, int* __restrict__ deg) {
    int e = blockIdx.x * 256 + threadIdx.x;
    if (e >= ET) return;
    int d = (e < N_EDGES) ? dst[e] : e - N_EDGES;
    atomicAdd(&deg[d], 1);
}

// ============ CSR scan, stage A: per-block (1024) inclusive scan ============
__global__ __launch_bounds__(1024) void scanA_kernel(
        const int* __restrict__ deg, int* __restrict__ tmp, int* __restrict__ bs) {
    const int i = blockIdx.x * 1024 + threadIdx.x;
    const int l = threadIdx.x & 63;
    const int w = threadIdx.x >> 6;           // 16 waves
    int v = (i < N_NODES) ? deg[i] : 0;
    int sc = v;
    #pragma unroll
    for (int off = 1; off < 64; off <<= 1) {
        int t = __shfl_up(sc, off);
        if (l >= off) sc += t;
    }
    __shared__ int ws[16];
    if (l == 63) ws[w] = sc;
    __syncthreads();
    if (threadIdx.x < 16) {
        int t = ws[threadIdx.x];
        #pragma unroll
        for (int off = 1; off < 16; off <<= 1) {
            int u = __shfl_up(t, off);
            if ((int)threadIdx.x >= off) t += u;
        }
        ws[threadIdx.x] = t;                  // inclusive wave sums
    }
    __syncthreads();
    int incl = sc + (w > 0 ? ws[w - 1] : 0);
    if (i < N_NODES) tmp[i] = incl;
    if (threadIdx.x == 1023) bs[blockIdx.x] = incl;
}

// ============ CSR scan, stage C: finalize rowptr + cursor ============
// Each block re-scans the 49 block sums itself (one wave) — no stage-B launch.
__global__ __launch_bounds__(256) void scanC_kernel(
        const int* __restrict__ tmp, const int* __restrict__ bs,
        const int* __restrict__ deg, int* __restrict__ rowptr,
        int* __restrict__ cursor) {
    __shared__ int boff_s[64];
    if (threadIdx.x < 64) {
        int l = threadIdx.x;
        int v = (l < SB) ? bs[l] : 0;
        int sc = v;
        #pragma unroll
        for (int off = 1; off < 64; off <<= 1) {
            int t = __shfl_up(sc, off);
            if (l >= off) sc += t;
        }
        boff_s[l] = sc - v;                   // exclusive
    }
    __syncthreads();
    int i = blockIdx.x * 256 + threadIdx.x;
    if (i >= N_NODES) return;
    int incl = tmp[i] + boff_s[i >> 10];
    rowptr[i + 1] = incl;
    cursor[i] = incl - deg[i];
    if (i == 0) rowptr[0] = 0;
}

// ============ CSR build: scatter src ids into dst buckets ============
__global__ __launch_bounds__(256) void scatter_kernel(
        const int* __restrict__ src, const int* __restrict__ dst,
        int* __restrict__ cursor, int* __restrict__ csr_src) {
    int e = blockIdx.x * 256 + threadIdx.x;
    if (e >= ET) return;
    int s, d;
    if (e < N_EDGES) { s = src[e]; d = dst[e]; } else { s = d = e - N_EDGES; }
    int pos = atomicAdd(&cursor[d], 1);
    csr_src[pos] = s;
}

// ============ Layer 1 fused: single-pass softmax-aggregate + bias + ELU ======
// One wave per dst node; unroll-8 gather for MLP. No max pass, no atomics.
__global__ __launch_bounds__(256) void agg1_fused_kernel(
        const int* __restrict__ rowptr, const int* __restrict__ csr_src,
        const float* __restrict__ a_src, const float* __restrict__ a_dst,
        const float* __restrict__ h1, const float* __restrict__ b1,
        float* __restrict__ hx) {
    int wid = (blockIdx.x * 256 + threadIdx.x) >> 6;
    int l = threadIdx.x & 63;
    if (wid >= N_NODES) return;
    int i = rowptr[wid];
    const int end = rowptr[wid + 1];
    const int hp = l >> 3;
    const float ad_p = a_dst[wid * 8 + hp];
    const int c = l * 4;
    float den = 0.f;
    float ax = 0.f, ay = 0.f, az = 0.f, aw = 0.f;
    for (; i + 8 <= end; i += 8) {
        int s[8];
        #pragma unroll
        for (int j = 0; j < 8; ++j) s[j] = csr_src[i + j];
        float4 v[8];
        #pragma unroll
        for (int j = 0; j < 8; ++j)
            v[j] = *(const float4*)(h1 + (size_t)s[j] * HID + c);
        float w[8];
        #pragma unroll
        for (int j = 0; j < 8; ++j)
            w[j] = __expf(lrelu(a_src[s[j] * 8 + hp] + ad_p));
        #pragma unroll
        for (int j = 0; j < 8; ++j) {
            den += w[j];
            ax += w[j] * v[j].x; ay += w[j] * v[j].y;
            az += w[j] * v[j].z; aw += w[j] * v[j].w;
        }
    }
    for (; i < end; ++i) {
        int s = csr_src[i];
        float4 v = *(const float4*)(h1 + (size_t)s * HID + c);
        float w = __expf(lrelu(a_src[s * 8 + hp] + ad_p));
        den += w;
        ax += w * v.x; ay += w * v.y; az += w * v.z; aw += w * v.w;
    }
    const float inv = 1.f / den;
    float4 bv = *(const float4*)(b1 + c);
    float o0 = ax * inv + bv.x, o1 = ay * inv + bv.y;
    float o2 = az * inv + bv.z, o3 = aw * inv + bv.w;
    o0 = o0 > 0.f ? o0 : expm1f(o0);
    o1 = o1 > 0.f ? o1 : expm1f(o1);
    o2 = o2 > 0.f ? o2 : expm1f(o2);
    o3 = o3 > 0.f ? o3 : expm1f(o3);
    *(float4*)(hx + (size_t)wid * HID + c) = make_float4(o0, o1, o2, o3);
}

// ============ layer 2 GEMM (wave per node) + attention logits ============
__global__ __launch_bounds__(256) void gemm2_kernel(
        const float* __restrict__ hx, const float* __restrict__ W2,
        const float* __restrict__ as2, const float* __restrict__ ad2,
        float* __restrict__ h2, float* __restrict__ a2s, float* __restrict__ a2d) {
    int t = blockIdx.x * 256 + threadIdx.x;
    int n = t >> 6, l = t & 63;
    if (n >= N_NODES) return;
    float4 xv = *(const float4*)(hx + (size_t)n * HID + l * 4);
    const float* w = W2 + l * 8;          // rows k=4l..4l+3, 2 cols each
    float4 w0 = *(const float4*)(w);
    float4 w1 = *(const float4*)(w + 4);
    float acc0 = xv.x * w0.x + xv.y * w0.z + xv.z * w1.x + xv.w * w1.z;
    float acc1 = xv.x * w0.y + xv.y * w0.w + xv.z * w1.y + xv.w * w1.w;
    #pragma unroll
    for (int off = 32; off; off >>= 1) {
        acc0 += __shfl_down(acc0, off);
        acc1 += __shfl_down(acc1, off);
    }
    if (l == 0) {
        h2[n * 2]     = acc0;
        h2[n * 2 + 1] = acc1;
        a2s[n] = acc0 * as2[0] + acc1 * as2[1];
        a2d[n] = acc0 * ad2[0] + acc1 * ad2[1];
    }
}

// ============ Layer 2 fused: 16 lanes per node (deg~33), 4 nodes/wave ========
__global__ __launch_bounds__(256) void agg2_fused_kernel(
        const int* __restrict__ rowptr, const int* __restrict__ csr_src,
        const float* __restrict__ a2s, const float* __restrict__ a2d,
        const float* __restrict__ h2, const float* __restrict__ b2,
        float* __restrict__ out) {
    int t = blockIdx.x * 256 + threadIdx.x;
    int node = t >> 4;
    int l = t & 15;
    if (node >= N_NODES) return;
    const int start = rowptr[node];
    const int end = rowptr[node + 1];
    const float adv = a2d[node];
    float sm = 0.f, acc0 = 0.f, acc1 = 0.f;
    for (int i = start + l; i < end; i += 16) {
        int s = csr_src[i];
        float w = __expf(lrelu(a2s[s] + adv));
        sm += w;
        acc0 += w * h2[s * 2];
        acc1 += w * h2[s * 2 + 1];
    }
    #pragma unroll
    for (int off = 8; off; off >>= 1) {       // xor stays within the 16-group
        sm   += __shfl_xor(sm, off);
        acc0 += __shfl_xor(acc0, off);
        acc1 += __shfl_xor(acc1, off);
    }
    if (l == 0) {
        out[node * 2]     = acc0 / sm + b2[0];
        out[node * 2 + 1] = acc1 / sm + b2[1];
    }
}

extern "C" void kernel_launch(void* const* d_in, const int* in_sizes, int n_in,
                              void* d_out, int out_size, void* d_ws, size_t ws_size,
                              hipStream_t stream) {
    (void)in_sizes; (void)n_in; (void)out_size; (void)ws_size;
    const float* x        = (const float*)d_in[0];
    const int*   ei       = (const int*)d_in[1];
    const float* W1       = (const float*)d_in[2];
    const float* att_src1 = (const float*)d_in[3];
    const float* att_dst1 = (const float*)d_in[4];
    const float* b1       = (const float*)d_in[5];
    const float* W2       = (const float*)d_in[6];
    const float* att_src2 = (const float*)d_in[7];
    const float* att_dst2 = (const float*)d_in[8];
    const float* b2       = (const float*)d_in[9];
    float* out = (float*)d_out;

    const int* src = ei;
    const int* dst = ei + N_EDGES;

    // ---- workspace carve-up (bytes) ----
    char* ws = (char*)d_ws;
    size_t off = 0;
    float* h1  = (float*)(ws + off); off += (size_t)N_NODES * HID * 4;     // 51.2 MB
    float* hx  = (float*)(ws + off); off += (size_t)N_NODES * HID * 4;     // 51.2 MB
    float* a_src1 = (float*)(ws + off); off += (size_t)N_NODES * HEADS * 4;
    float* a_dst1 = (float*)(ws + off); off += (size_t)N_NODES * HEADS * 4;
    float* h2  = (float*)(ws + off); off += (size_t)N_NODES * OUT_C * 4;
    float* a2s = (float*)(ws + off); off += (size_t)N_NODES * 4;
    float* a2d = (float*)(ws + off); off += (size_t)N_NODES * 4;
    int* deg    = (int*)(ws + off); off += (size_t)N_NODES * 4;
    int* rowptr = (int*)(ws + off); off += (size_t)(N_NODES + 1) * 4;
    int* cursor = (int*)(ws + off); off += (size_t)N_NODES * 4;
    int* tmp    = (int*)(ws + off); off += (size_t)N_NODES * 4;
    int* bs     = (int*)(ws + off); off += 64 * 4;
    int* csr_src = (int*)(ws + off); off += (size_t)ET * 4;                // 6.6 MB

    hipMemsetAsync(deg, 0, (size_t)N_NODES * 4, stream);

    const int EB = (ET + 255) / 256;
    const int NW = (N_NODES * 64 + 255) / 256;        // wave-per-node grids

    // ---- CSR build (dst buckets) ----
    hist_kernel<<<EB, 256, 0, stream>>>(dst, deg);
    scanA_kernel<<<SB, 1024, 0, stream>>>(deg, tmp, bs);
    scanC_kernel<<<(N_NODES + 255) / 256, 256, 0, stream>>>(tmp, bs, deg, rowptr, cursor);
    scatter_kernel<<<EB, 256, 0, stream>>>(src, dst, cursor, csr_src);

    // ---- layer 1 ----
    gemm1_att_kernel<<<(N_NODES + 63) / 64, 256, 0, stream>>>(
        x, W1, att_src1, att_dst1, h1, a_src1, a_dst1);
    agg1_fused_kernel<<<NW, 256, 0, stream>>>(
        rowptr, csr_src, a_src1, a_dst1, h1, b1, hx);

    // ---- layer 2 ----
    gemm2_kernel<<<NW, 256, 0, stream>>>(hx, W2, att_src2, att_dst2, h2, a2s, a2d);
    agg2_fused_kernel<<<(N_NODES * 16 + 255) / 256, 256, 0, stream>>>(
        rowptr, csr_src, a2s, a2d, h2, b2, out);
}

// Round 5
// 591.088 us; speedup vs baseline: 12.4983x; 1.1942x over previous
//
#include <hip/hip_runtime.h>
#include <hip/hip_bf16.h>
#include <math.h>

#define N_NODES 50000
#define N_EDGES 1600000
#define ET (N_EDGES + N_NODES)   // with self loops
#define IN_C 165
#define HID 256
#define HEADS 8
#define C1 32
#define OUT_C 2
#define NEG_SLOPE 0.2f
#define SB ((N_NODES + 1023) / 1024)       // 49 scan blocks
#define GEMM_BLOCKS ((N_NODES + 63) / 64)  // 782
#define GA (GEMM_BLOCKS / 2)               // 391: gemm blocks co-launched with hist
#define GB (GEMM_BLOCKS - GA)              // 391: gemm blocks co-launched with scatter
#define EBLK ((ET + 255) / 256)            // 6446 edge blocks

__device__ inline float lrelu(float v) { return v > 0.f ? v : NEG_SLOPE * v; }

// ============ shared gemm1+att block body (called from both fused kernels) ===
// 64 rows x 256 cols; thread = 4 rows x 16 cols (64 FMA per k).
__device__ __forceinline__ void gemm1_att_block(
        int row0, const float* __restrict__ x, const float* __restrict__ W,
        const float* __restrict__ att_src, const float* __restrict__ att_dst,
        float* __restrict__ h, float* __restrict__ a_src, float* __restrict__ a_dst,
        float* xs, float* sh_s, float* sh_d) {
    const int tid = threadIdx.x;
    const int nrow = (N_NODES - row0 < 64) ? (N_NODES - row0) : 64;
    const int lim = nrow * IN_C;
    for (int idx = tid; idx < 64 * IN_C; idx += 256)
        xs[idx] = (idx < lim) ? x[(size_t)row0 * IN_C + idx] : 0.f;
    __syncthreads();
    const int tr = tid & 15;                  // 16 row-groups of 4
    const int cq = tid >> 4;                  // col-group 0..15
    const int c0 = cq * 16;
    float acc[4][16];
    #pragma unroll
    for (int j = 0; j < 4; ++j)
        #pragma unroll
        for (int q = 0; q < 16; ++q) acc[j][q] = 0.f;
    const float* xb = xs + (tr * 4) * IN_C;
    for (int k = 0; k < IN_C; ++k) {
        float xv0 = xb[k];
        float xv1 = xb[IN_C + k];
        float xv2 = xb[2 * IN_C + k];
        float xv3 = xb[3 * IN_C + k];
        const float* wp = W + k * HID + c0;
        #pragma unroll
        for (int q = 0; q < 4; ++q) {
            float4 wq = *(const float4*)(wp + q * 4);
            acc[0][q*4+0] += xv0 * wq.x; acc[0][q*4+1] += xv0 * wq.y;
            acc[0][q*4+2] += xv0 * wq.z; acc[0][q*4+3] += xv0 * wq.w;
            acc[1][q*4+0] += xv1 * wq.x; acc[1][q*4+1] += xv1 * wq.y;
            acc[1][q*4+2] += xv1 * wq.z; acc[1][q*4+3] += xv1 * wq.w;
            acc[2][q*4+0] += xv2 * wq.x; acc[2][q*4+1] += xv2 * wq.y;
            acc[2][q*4+2] += xv2 * wq.z; acc[2][q*4+3] += xv2 * wq.w;
            acc[3][q*4+0] += xv3 * wq.x; acc[3][q*4+1] += xv3 * wq.y;
            acc[3][q*4+2] += xv3 * wq.z; acc[3][q*4+3] += xv3 * wq.w;
        }
    }
    #pragma unroll
    for (int j = 0; j < 4; ++j) {
        int gr = row0 + tr * 4 + j;
        if (gr < N_NODES) {
            float* o = h + (size_t)gr * HID + c0;
            #pragma unroll
            for (int q = 0; q < 4; ++q)
                *(float4*)(o + q * 4) = make_float4(acc[j][q*4+0], acc[j][q*4+1],
                                                    acc[j][q*4+2], acc[j][q*4+3]);
        }
    }
    // fused attention partial dots: cols [c0,c0+16) = head cq>>1, offset (cq&1)*16
    {
        const int hd = cq >> 1;
        const float* as = att_src + hd * C1 + (cq & 1) * 16;
        const float* ad = att_dst + hd * C1 + (cq & 1) * 16;
        float av[16], dv[16];
        #pragma unroll
        for (int q = 0; q < 4; ++q) {
            float4 a4 = *(const float4*)(as + q * 4);
            float4 d4 = *(const float4*)(ad + q * 4);
            av[q*4+0]=a4.x; av[q*4+1]=a4.y; av[q*4+2]=a4.z; av[q*4+3]=a4.w;
            dv[q*4+0]=d4.x; dv[q*4+1]=d4.y; dv[q*4+2]=d4.z; dv[q*4+3]=d4.w;
        }
        #pragma unroll
        for (int j = 0; j < 4; ++j) {
            float ps = 0.f, pd = 0.f;
            #pragma unroll
            for (int q = 0; q < 16; ++q) {
                ps += acc[j][q] * av[q];
                pd += acc[j][q] * dv[q];
            }
            sh_s[(tr * 4 + j) * 16 + cq] = ps;
            sh_d[(tr * 4 + j) * 16 + cq] = pd;
        }
    }
    __syncthreads();
    #pragma unroll
    for (int o = tid; o < 512; o += 256) {    // (row, head) pairs
        int r = o >> 3, hd = o & 7;
        int gr = row0 + r;
        if (gr < N_NODES) {
            a_src[gr * 8 + hd] = sh_s[r * 16 + hd * 2] + sh_s[r * 16 + hd * 2 + 1];
            a_dst[gr * 8 + hd] = sh_d[r * 16 + hd * 2] + sh_d[r * 16 + hd * 2 + 1];
        }
    }
}

// ============ fused A: gemm half 1 || dst-histogram ============
__global__ __launch_bounds__(256) void fusedA_kernel(
        const float* __restrict__ x, const float* __restrict__ W,
        const float* __restrict__ att_src, const float* __restrict__ att_dst,
        float* __restrict__ h, float* __restrict__ a_src, float* __restrict__ a_dst,
        const int* __restrict__ dst, int* __restrict__ deg) {
    __shared__ float xs[64 * IN_C];
    __shared__ float sh_s[64 * 16];
    __shared__ float sh_d[64 * 16];
    if (blockIdx.x < GA) {
        gemm1_att_block(blockIdx.x * 64, x, W, att_src, att_dst,
                        h, a_src, a_dst, xs, sh_s, sh_d);
    } else {
        int e = (blockIdx.x - GA) * 256 + threadIdx.x;
        if (e < ET) {
            int d = (e < N_EDGES) ? dst[e] : e - N_EDGES;
            atomicAdd(&deg[d], 1);
        }
    }
}

// ============ CSR scan, stage A ============
__global__ __launch_bounds__(1024) void scanA_kernel(
        const int* __restrict__ deg, int* __restrict__ tmp, int* __restrict__ bs) {
    const int i = blockIdx.x * 1024 + threadIdx.x;
    const int l = threadIdx.x & 63;
    const int w = threadIdx.x >> 6;
    int v = (i < N_NODES) ? deg[i] : 0;
    int sc = v;
    #pragma unroll
    for (int off = 1; off < 64; off <<= 1) {
        int t = __shfl_up(sc, off);
        if (l >= off) sc += t;
    }
    __shared__ int ws[16];
    if (l == 63) ws[w] = sc;
    __syncthreads();
    if (threadIdx.x < 16) {
        int t = ws[threadIdx.x];
        #pragma unroll
        for (int off = 1; off < 16; off <<= 1) {
            int u = __shfl_up(t, off);
            if ((int)threadIdx.x >= off) t += u;
        }
        ws[threadIdx.x] = t;
    }
    __syncthreads();
    int incl = sc + (w > 0 ? ws[w - 1] : 0);
    if (i < N_NODES) tmp[i] = incl;
    if (threadIdx.x == 1023) bs[blockIdx.x] = incl;
}

// ============ CSR scan, stage C: finalize rowptr + cursor ============
__global__ __launch_bounds__(256) void scanC_kernel(
        const int* __restrict__ tmp, const int* __restrict__ bs,
        const int* __restrict__ deg, int* __restrict__ rowptr,
        int* __restrict__ cursor) {
    __shared__ int boff_s[64];
    if (threadIdx.x < 64) {
        int l = threadIdx.x;
        int v = (l < SB) ? bs[l] : 0;
        int sc = v;
        #pragma unroll
        for (int off = 1; off < 64; off <<= 1) {
            int t = __shfl_up(sc, off);
            if (l >= off) sc += t;
        }
        boff_s[l] = sc - v;
    }
    __syncthreads();
    int i = blockIdx.x * 256 + threadIdx.x;
    if (i >= N_NODES) return;
    int incl = tmp[i] + boff_s[i >> 10];
    rowptr[i + 1] = incl;
    cursor[i] = incl - deg[i];
    if (i == 0) rowptr[0] = 0;
}

// ============ fused B: gemm half 2 || scatter ============
__global__ __launch_bounds__(256) void fusedB_kernel(
        const float* __restrict__ x, const float* __restrict__ W,
        const float* __restrict__ att_src, const float* __restrict__ att_dst,
        float* __restrict__ h, float* __restrict__ a_src, float* __restrict__ a_dst,
        const int* __restrict__ src, const int* __restrict__ dst,
        int* __restrict__ cursor, int* __restrict__ csr_src) {
    __shared__ float xs[64 * IN_C];
    __shared__ float sh_s[64 * 16];
    __shared__ float sh_d[64 * 16];
    if (blockIdx.x < GB) {
        gemm1_att_block((GA + blockIdx.x) * 64, x, W, att_src, att_dst,
                        h, a_src, a_dst, xs, sh_s, sh_d);
    } else {
        int e = (blockIdx.x - GB) * 256 + threadIdx.x;
        if (e < ET) {
            int s, d;
            if (e < N_EDGES) { s = src[e]; d = dst[e]; } else { s = d = e - N_EDGES; }
            int pos = atomicAdd(&cursor[d], 1);
            csr_src[pos] = s;
        }
    }
}

// ============ Layer 1 fused: softmax-aggregate + bias + ELU + layer-2 GEMM ===
// One wave per dst node. hx row lives only in registers; epilogue computes
// h2[n] = hx @ W2 and the layer-2 attention logits. hx never hits memory.
__global__ __launch_bounds__(256) void agg1_fused_kernel(
        const int* __restrict__ rowptr, const int* __restrict__ csr_src,
        const float* __restrict__ a_src, const float* __restrict__ a_dst,
        const float* __restrict__ h1, const float* __restrict__ b1,
        const float* __restrict__ W2,
        const float* __restrict__ as2, const float* __restrict__ ad2,
        float* __restrict__ h2, float* __restrict__ a2s, float* __restrict__ a2d) {
    int wid = (blockIdx.x * 256 + threadIdx.x) >> 6;
    int l = threadIdx.x & 63;
    if (wid >= N_NODES) return;
    int i = rowptr[wid];
    const int end = rowptr[wid + 1];
    const int hp = l >> 3;
    const float ad_p = a_dst[wid * 8 + hp];
    const int c = l * 4;
    float den = 0.f;
    float ax = 0.f, ay = 0.f, az = 0.f, aw = 0.f;
    for (; i + 8 <= end; i += 8) {
        int s[8];
        #pragma unroll
        for (int j = 0; j < 8; ++j) s[j] = csr_src[i + j];
        float4 v[8];
        #pragma unroll
        for (int j = 0; j < 8; ++j)
            v[j] = *(const float4*)(h1 + (size_t)s[j] * HID + c);
        float w[8];
        #pragma unroll
        for (int j = 0; j < 8; ++j)
            w[j] = __expf(lrelu(a_src[s[j] * 8 + hp] + ad_p));
        #pragma unroll
        for (int j = 0; j < 8; ++j) {
            den += w[j];
            ax += w[j] * v[j].x; ay += w[j] * v[j].y;
            az += w[j] * v[j].z; aw += w[j] * v[j].w;
        }
    }
    for (; i < end; ++i) {
        int s = csr_src[i];
        float4 v = *(const float4*)(h1 + (size_t)s * HID + c);
        float w = __expf(lrelu(a_src[s * 8 + hp] + ad_p));
        den += w;
        ax += w * v.x; ay += w * v.y; az += w * v.z; aw += w * v.w;
    }
    const float inv = 1.f / den;
    float4 bv = *(const float4*)(b1 + c);
    float o0 = ax * inv + bv.x, o1 = ay * inv + bv.y;
    float o2 = az * inv + bv.z, o3 = aw * inv + bv.w;
    o0 = o0 > 0.f ? o0 : expm1f(o0);
    o1 = o1 > 0.f ? o1 : expm1f(o1);
    o2 = o2 > 0.f ? o2 : expm1f(o2);
    o3 = o3 > 0.f ? o3 : expm1f(o3);
    // ---- fused layer-2 GEMM: lane owns hx channels c..c+3 ----
    const float* wv = W2 + l * 8;             // rows c..c+3, 2 cols, row-major
    float4 w0 = *(const float4*)(wv);
    float4 w1 = *(const float4*)(wv + 4);
    float p0 = o0 * w0.x + o1 * w0.z + o2 * w1.x + o3 * w1.z;
    float p1 = o0 * w0.y + o1 * w0.w + o2 * w1.y + o3 * w1.w;
    #pragma unroll
    for (int off = 32; off; off >>= 1) {
        p0 += __shfl_down(p0, off);
        p1 += __shfl_down(p1, off);
    }
    if (l == 0) {
        h2[wid * 2]     = p0;
        h2[wid * 2 + 1] = p1;
        a2s[wid] = p0 * as2[0] + p1 * as2[1];
        a2d[wid] = p0 * ad2[0] + p1 * ad2[1];
    }
}

// ============ Layer 2 fused: 16 lanes per node (deg~33), 4 nodes/wave ========
__global__ __launch_bounds__(256) void agg2_fused_kernel(
        const int* __restrict__ rowptr, const int* __restrict__ csr_src,
        const float* __restrict__ a2s, const float* __restrict__ a2d,
        const float* __restrict__ h2, const float* __restrict__ b2,
        float* __restrict__ out) {
    int t = blockIdx.x * 256 + threadIdx.x;
    int node = t >> 4;
    int l = t & 15;
    if (node >= N_NODES) return;
    const int start = rowptr[node];
    const int end = rowptr[node + 1];
    const float adv = a2d[node];
    float sm = 0.f, acc0 = 0.f, acc1 = 0.f;
    for (int i = start + l; i < end; i += 16) {
        int s = csr_src[i];
        float w = __expf(lrelu(a2s[s] + adv));
        sm += w;
        acc0 += w * h2[s * 2];
        acc1 += w * h2[s * 2 + 1];
    }
    #pragma unroll
    for (int off = 8; off; off >>= 1) {
        sm   += __shfl_xor(sm, off);
        acc0 += __shfl_xor(acc0, off);
        acc1 += __shfl_xor(acc1, off);
    }
    if (l == 0) {
        out[node * 2]     = acc0 / sm + b2[0];
        out[node * 2 + 1] = acc1 / sm + b2[1];
    }
}

extern "C" void kernel_launch(void* const* d_in, const int* in_sizes, int n_in,
                              void* d_out, int out_size, void* d_ws, size_t ws_size,
                              hipStream_t stream) {
    (void)in_sizes; (void)n_in; (void)out_size; (void)ws_size;
    const float* x        = (const float*)d_in[0];
    const int*   ei       = (const int*)d_in[1];
    const float* W1       = (const float*)d_in[2];
    const float* att_src1 = (const float*)d_in[3];
    const float* att_dst1 = (const float*)d_in[4];
    const float* b1       = (const float*)d_in[5];
    const float* W2       = (const float*)d_in[6];
    const float* att_src2 = (const float*)d_in[7];
    const float* att_dst2 = (const float*)d_in[8];
    const float* b2       = (const float*)d_in[9];
    float* out = (float*)d_out;

    const int* src = ei;
    const int* dst = ei + N_EDGES;

    // ---- workspace carve-up (bytes) ----
    char* ws = (char*)d_ws;
    size_t off = 0;
    float* h1  = (float*)(ws + off); off += (size_t)N_NODES * HID * 4;     // 51.2 MB
    float* a_src1 = (float*)(ws + off); off += (size_t)N_NODES * HEADS * 4;
    float* a_dst1 = (float*)(ws + off); off += (size_t)N_NODES * HEADS * 4;
    float* h2  = (float*)(ws + off); off += (size_t)N_NODES * OUT_C * 4;
    float* a2s = (float*)(ws + off); off += (size_t)N_NODES * 4;
    float* a2d = (float*)(ws + off); off += (size_t)N_NODES * 4;
    int* deg    = (int*)(ws + off); off += (size_t)N_NODES * 4;
    int* rowptr = (int*)(ws + off); off += (size_t)(N_NODES + 1) * 4;
    int* cursor = (int*)(ws + off); off += (size_t)N_NODES * 4;
    int* tmp    = (int*)(ws + off); off += (size_t)N_NODES * 4;
    int* bs     = (int*)(ws + off); off += 64 * 4;
    int* csr_src = (int*)(ws + off); off += (size_t)ET * 4;                // 6.6 MB

    hipMemsetAsync(deg, 0, (size_t)N_NODES * 4, stream);

    const int NW = (N_NODES * 64 + 255) / 256;        // wave-per-node grids

    // ---- gemm half A || hist ----
    fusedA_kernel<<<GA + EBLK, 256, 0, stream>>>(
        x, W1, att_src1, att_dst1, h1, a_src1, a_dst1, dst, deg);
    scanA_kernel<<<SB, 1024, 0, stream>>>(deg, tmp, bs);
    scanC_kernel<<<(N_NODES + 255) / 256, 256, 0, stream>>>(tmp, bs, deg, rowptr, cursor);
    // ---- gemm half B || scatter ----
    fusedB_kernel<<<GB + EBLK, 256, 0, stream>>>(
        x, W1, att_src1, att_dst1, h1, a_src1, a_dst1, src, dst, cursor, csr_src);

    // ---- layer 1 aggregate + ELU + layer 2 GEMM (fused) ----
    agg1_fused_kernel<<<NW, 256, 0, stream>>>(
        rowptr, csr_src, a_src1, a_dst1, h1, b1, W2, att_src2, att_dst2,
        h2, a2s, a2d);

    // ---- layer 2 aggregate ----
    agg2_fused_kernel<<<(N_NODES * 16 + 255) / 256, 256, 0, stream>>>(
        rowptr, csr_src, a2s, a2d, h2, b2, out);
}

// Round 6
// 438.883 us; speedup vs baseline: 16.8327x; 1.3468x over previous
//
#include <hip/hip_runtime.h>
#include <hip/hip_bf16.h>
#include <math.h>

#define N_NODES 50000
#define N_EDGES 1600000
#define ET (N_EDGES + N_NODES)   // with self loops
#define IN_C 165
#define HID 256
#define HEADS 8
#define C1 32
#define OUT_C 2
#define NEG_SLOPE 0.2f
#define SB ((N_NODES + 1023) / 1024)       // 49 scan blocks
#define GEMM_BLOCKS ((N_NODES + 63) / 64)  // 782
#define GA (GEMM_BLOCKS / 2)               // 391: gemm blocks co-launched with hist
#define GB (GEMM_BLOCKS - GA)              // 391: gemm blocks co-launched with scatter
#define EBLK ((ET + 255) / 256)            // 6446 edge blocks

__device__ inline float lrelu(float v) { return v > 0.f ? v : NEG_SLOPE * v; }

// fp32 -> bf16 bits, round-to-nearest-even
__device__ inline unsigned short f32_bf16(float f) {
    unsigned u = __float_as_uint(f);
    return (unsigned short)((u + 0x7FFFu + ((u >> 16) & 1u)) >> 16);
}

// ============ shared gemm1+att block body ============
// 64 rows x 256 cols; thread = 4 rows x 16 cols (64 FMA per k).
// h is stored as packed bf16 (RNE); attention logits stay fp32 (from fp32 acc).
__device__ __forceinline__ void gemm1_att_block(
        int row0, const float* __restrict__ x, const float* __restrict__ W,
        const float* __restrict__ att_src, const float* __restrict__ att_dst,
        unsigned short* __restrict__ h, float* __restrict__ a_src,
        float* __restrict__ a_dst,
        float* xs, float* sh_s, float* sh_d) {
    const int tid = threadIdx.x;
    const int nrow = (N_NODES - row0 < 64) ? (N_NODES - row0) : 64;
    const int lim = nrow * IN_C;
    for (int idx = tid; idx < 64 * IN_C; idx += 256)
        xs[idx] = (idx < lim) ? x[(size_t)row0 * IN_C + idx] : 0.f;
    __syncthreads();
    const int tr = tid & 15;                  // 16 row-groups of 4
    const int cq = tid >> 4;                  // col-group 0..15
    const int c0 = cq * 16;
    float acc[4][16];
    #pragma unroll
    for (int j = 0; j < 4; ++j)
        #pragma unroll
        for (int q = 0; q < 16; ++q) acc[j][q] = 0.f;
    const float* xb = xs + (tr * 4) * IN_C;
    for (int k = 0; k < IN_C; ++k) {
        float xv0 = xb[k];
        float xv1 = xb[IN_C + k];
        float xv2 = xb[2 * IN_C + k];
        float xv3 = xb[3 * IN_C + k];
        const float* wp = W + k * HID + c0;
        #pragma unroll
        for (int q = 0; q < 4; ++q) {
            float4 wq = *(const float4*)(wp + q * 4);
            acc[0][q*4+0] += xv0 * wq.x; acc[0][q*4+1] += xv0 * wq.y;
            acc[0][q*4+2] += xv0 * wq.z; acc[0][q*4+3] += xv0 * wq.w;
            acc[1][q*4+0] += xv1 * wq.x; acc[1][q*4+1] += xv1 * wq.y;
            acc[1][q*4+2] += xv1 * wq.z; acc[1][q*4+3] += xv1 * wq.w;
            acc[2][q*4+0] += xv2 * wq.x; acc[2][q*4+1] += xv2 * wq.y;
            acc[2][q*4+2] += xv2 * wq.z; acc[2][q*4+3] += xv2 * wq.w;
            acc[3][q*4+0] += xv3 * wq.x; acc[3][q*4+1] += xv3 * wq.y;
            acc[3][q*4+2] += xv3 * wq.z; acc[3][q*4+3] += xv3 * wq.w;
        }
    }
    // store h tile as packed bf16 (16 cols = 32 B = 2x uint4)
    #pragma unroll
    for (int j = 0; j < 4; ++j) {
        int gr = row0 + tr * 4 + j;
        if (gr < N_NODES) {
            unsigned p[8];
            #pragma unroll
            for (int q = 0; q < 8; ++q)
                p[q] = (unsigned)f32_bf16(acc[j][2*q]) |
                       ((unsigned)f32_bf16(acc[j][2*q+1]) << 16);
            unsigned short* o = h + (size_t)gr * HID + c0;
            *(uint4*)(o)     = make_uint4(p[0], p[1], p[2], p[3]);
            *(uint4*)(o + 8) = make_uint4(p[4], p[5], p[6], p[7]);
        }
    }
    // fused attention partial dots (fp32 acc): cols c0.. = head cq>>1
    {
        const int hd = cq >> 1;
        const float* as = att_src + hd * C1 + (cq & 1) * 16;
        const float* ad = att_dst + hd * C1 + (cq & 1) * 16;
        float av[16], dv[16];
        #pragma unroll
        for (int q = 0; q < 4; ++q) {
            float4 a4 = *(const float4*)(as + q * 4);
            float4 d4 = *(const float4*)(ad + q * 4);
            av[q*4+0]=a4.x; av[q*4+1]=a4.y; av[q*4+2]=a4.z; av[q*4+3]=a4.w;
            dv[q*4+0]=d4.x; dv[q*4+1]=d4.y; dv[q*4+2]=d4.z; dv[q*4+3]=d4.w;
        }
        #pragma unroll
        for (int j = 0; j < 4; ++j) {
            float ps = 0.f, pd = 0.f;
            #pragma unroll
            for (int q = 0; q < 16; ++q) {
                ps += acc[j][q] * av[q];
                pd += acc[j][q] * dv[q];
            }
            sh_s[(tr * 4 + j) * 16 + cq] = ps;
            sh_d[(tr * 4 + j) * 16 + cq] = pd;
        }
    }
    __syncthreads();
    #pragma unroll
    for (int o = tid; o < 512; o += 256) {    // (row, head) pairs
        int r = o >> 3, hd = o & 7;
        int gr = row0 + r;
        if (gr < N_NODES) {
            a_src[gr * 8 + hd] = sh_s[r * 16 + hd * 2] + sh_s[r * 16 + hd * 2 + 1];
            a_dst[gr * 8 + hd] = sh_d[r * 16 + hd * 2] + sh_d[r * 16 + hd * 2 + 1];
        }
    }
}

// ============ fused A: gemm half 1 || dst-histogram ============
__global__ __launch_bounds__(256) void fusedA_kernel(
        const float* __restrict__ x, const float* __restrict__ W,
        const float* __restrict__ att_src, const float* __restrict__ att_dst,
        unsigned short* __restrict__ h, float* __restrict__ a_src,
        float* __restrict__ a_dst,
        const int* __restrict__ dst, int* __restrict__ deg) {
    __shared__ float xs[64 * IN_C];
    __shared__ float sh_s[64 * 16];
    __shared__ float sh_d[64 * 16];
    if (blockIdx.x < GA) {
        gemm1_att_block(blockIdx.x * 64, x, W, att_src, att_dst,
                        h, a_src, a_dst, xs, sh_s, sh_d);
    } else {
        int e = (blockIdx.x - GA) * 256 + threadIdx.x;
        if (e < ET) {
            int d = (e < N_EDGES) ? dst[e] : e - N_EDGES;
            atomicAdd(&deg[d], 1);
        }
    }
}

// ============ CSR scan, stage A ============
__global__ __launch_bounds__(1024) void scanA_kernel(
        const int* __restrict__ deg, int* __restrict__ tmp, int* __restrict__ bs) {
    const int i = blockIdx.x * 1024 + threadIdx.x;
    const int l = threadIdx.x & 63;
    const int w = threadIdx.x >> 6;
    int v = (i < N_NODES) ? deg[i] : 0;
    int sc = v;
    #pragma unroll
    for (int off = 1; off < 64; off <<= 1) {
        int t = __shfl_up(sc, off);
        if (l >= off) sc += t;
    }
    __shared__ int ws[16];
    if (l == 63) ws[w] = sc;
    __syncthreads();
    if (threadIdx.x < 16) {
        int t = ws[threadIdx.x];
        #pragma unroll
        for (int off = 1; off < 16; off <<= 1) {
            int u = __shfl_up(t, off);
            if ((int)threadIdx.x >= off) t += u;
        }
        ws[threadIdx.x] = t;
    }
    __syncthreads();
    int incl = sc + (w > 0 ? ws[w - 1] : 0);
    if (i < N_NODES) tmp[i] = incl;
    if (threadIdx.x == 1023) bs[blockIdx.x] = incl;
}

// ============ CSR scan, stage C: finalize rowptr + cursor ============
__global__ __launch_bounds__(256) void scanC_kernel(
        const int* __restrict__ tmp, const int* __restrict__ bs,
        const int* __restrict__ deg, int* __restrict__ rowptr,
        int* __restrict__ cursor) {
    __shared__ int boff_s[64];
    if (threadIdx.x < 64) {
        int l = threadIdx.x;
        int v = (l < SB) ? bs[l] : 0;
        int sc = v;
        #pragma unroll
        for (int off = 1; off < 64; off <<= 1) {
            int t = __shfl_up(sc, off);
            if (l >= off) sc += t;
        }
        boff_s[l] = sc - v;
    }
    __syncthreads();
    int i = blockIdx.x * 256 + threadIdx.x;
    if (i >= N_NODES) return;
    int incl = tmp[i] + boff_s[i >> 10];
    rowptr[i + 1] = incl;
    cursor[i] = incl - deg[i];
    if (i == 0) rowptr[0] = 0;
}

// ============ fused B: gemm half 2 || scatter ============
__global__ __launch_bounds__(256) void fusedB_kernel(
        const float* __restrict__ x, const float* __restrict__ W,
        const float* __restrict__ att_src, const float* __restrict__ att_dst,
        unsigned short* __restrict__ h, float* __restrict__ a_src,
        float* __restrict__ a_dst,
        const int* __restrict__ src, const int* __restrict__ dst,
        int* __restrict__ cursor, int* __restrict__ csr_src) {
    __shared__ float xs[64 * IN_C];
    __shared__ float sh_s[64 * 16];
    __shared__ float sh_d[64 * 16];
    if (blockIdx.x < GB) {
        gemm1_att_block((GA + blockIdx.x) * 64, x, W, att_src, att_dst,
                        h, a_src, a_dst, xs, sh_s, sh_d);
    } else {
        int e = (blockIdx.x - GB) * 256 + threadIdx.x;
        if (e < ET) {
            int s, d;
            if (e < N_EDGES) { s = src[e]; d = dst[e]; } else { s = d = e - N_EDGES; }
            int pos = atomicAdd(&cursor[d], 1);
            csr_src[pos] = s;
        }
    }
}

// ============ Layer 1 fused: softmax-aggregate(bf16 gather) + bias + ELU
//              + layer-2 GEMM.  One wave per dst node; hx never hits memory. ==
__global__ __launch_bounds__(256) void agg1_fused_kernel(
        const int* __restrict__ rowptr, const int* __restrict__ csr_src,
        const float* __restrict__ a_src, const float* __restrict__ a_dst,
        const unsigned short* __restrict__ h1, const float* __restrict__ b1,
        const float* __restrict__ W2,
        const float* __restrict__ as2, const float* __restrict__ ad2,
        float* __restrict__ h2, float* __restrict__ a2s, float* __restrict__ a2d) {
    int wid = (blockIdx.x * 256 + threadIdx.x) >> 6;
    int l = threadIdx.x & 63;
    if (wid >= N_NODES) return;
    int i = rowptr[wid];
    const int end = rowptr[wid + 1];
    const int hp = l >> 3;
    const float ad_p = a_dst[wid * 8 + hp];
    const int c = l * 4;                      // ushort units
    float den = 0.f;
    float ax = 0.f, ay = 0.f, az = 0.f, aw = 0.f;
    for (; i + 8 <= end; i += 8) {
        int s[8];
        #pragma unroll
        for (int j = 0; j < 8; ++j) s[j] = csr_src[i + j];
        uint2 v[8];
        #pragma unroll
        for (int j = 0; j < 8; ++j)
            v[j] = *(const uint2*)(h1 + (size_t)s[j] * HID + c);
        float w[8];
        #pragma unroll
        for (int j = 0; j < 8; ++j)
            w[j] = __expf(lrelu(a_src[s[j] * 8 + hp] + ad_p));
        #pragma unroll
        for (int j = 0; j < 8; ++j) {
            den += w[j];
            ax += w[j] * __uint_as_float(v[j].x << 16);
            ay += w[j] * __uint_as_float(v[j].x & 0xFFFF0000u);
            az += w[j] * __uint_as_float(v[j].y << 16);
            aw += w[j] * __uint_as_float(v[j].y & 0xFFFF0000u);
        }
    }
    for (; i < end; ++i) {
        int s = csr_src[i];
        uint2 v = *(const uint2*)(h1 + (size_t)s * HID + c);
        float w = __expf(lrelu(a_src[s * 8 + hp] + ad_p));
        den += w;
        ax += w * __uint_as_float(v.x << 16);
        ay += w * __uint_as_float(v.x & 0xFFFF0000u);
        az += w * __uint_as_float(v.y << 16);
        aw += w * __uint_as_float(v.y & 0xFFFF0000u);
    }
    const float inv = 1.f / den;
    float4 bv = *(const float4*)(b1 + c);
    float o0 = ax * inv + bv.x, o1 = ay * inv + bv.y;
    float o2 = az * inv + bv.z, o3 = aw * inv + bv.w;
    o0 = o0 > 0.f ? o0 : expm1f(o0);
    o1 = o1 > 0.f ? o1 : expm1f(o1);
    o2 = o2 > 0.f ? o2 : expm1f(o2);
    o3 = o3 > 0.f ? o3 : expm1f(o3);
    // ---- fused layer-2 GEMM: lane owns hx channels c..c+3 ----
    const float* wv = W2 + l * 8;             // rows c..c+3, 2 cols, row-major
    float4 w0 = *(const float4*)(wv);
    float4 w1 = *(const float4*)(wv + 4);
    float p0 = o0 * w0.x + o1 * w0.z + o2 * w1.x + o3 * w1.z;
    float p1 = o0 * w0.y + o1 * w0.w + o2 * w1.y + o3 * w1.w;
    #pragma unroll
    for (int off = 32; off; off >>= 1) {
        p0 += __shfl_down(p0, off);
        p1 += __shfl_down(p1, off);
    }
    if (l == 0) {
        h2[wid * 2]     = p0;
        h2[wid * 2 + 1] = p1;
        a2s[wid] = p0 * as2[0] + p1 * as2[1];
        a2d[wid] = p0 * ad2[0] + p1 * ad2[1];
    }
}

// ============ Layer 2 fused: 16 lanes per node (deg~33), 4 nodes/wave ========
__global__ __launch_bounds__(256) void agg2_fused_kernel(
        const int* __restrict__ rowptr, const int* __restrict__ csr_src,
        const float* __restrict__ a2s, const float* __restrict__ a2d,
        const float* __restrict__ h2, const float* __restrict__ b2,
        float* __restrict__ out) {
    int t = blockIdx.x * 256 + threadIdx.x;
    int node = t >> 4;
    int l = t & 15;
    if (node >= N_NODES) return;
    const int start = rowptr[node];
    const int end = rowptr[node + 1];
    const float adv = a2d[node];
    float sm = 0.f, acc0 = 0.f, acc1 = 0.f;
    for (int i = start + l; i < end; i += 16) {
        int s = csr_src[i];
        float w = __expf(lrelu(a2s[s] + adv));
        sm += w;
        acc0 += w * h2[s * 2];
        acc1 += w * h2[s * 2 + 1];
    }
    #pragma unroll
    for (int off = 8; off; off >>= 1) {
        sm   += __shfl_xor(sm, off);
        acc0 += __shfl_xor(acc0, off);
        acc1 += __shfl_xor(acc1, off);
    }
    if (l == 0) {
        out[node * 2]     = acc0 / sm + b2[0];
        out[node * 2 + 1] = acc1 / sm + b2[1];
    }
}

extern "C" void kernel_launch(void* const* d_in, const int* in_sizes, int n_in,
                              void* d_out, int out_size, void* d_ws, size_t ws_size,
                              hipStream_t stream) {
    (void)in_sizes; (void)n_in; (void)out_size; (void)ws_size;
    const float* x        = (const float*)d_in[0];
    const int*   ei       = (const int*)d_in[1];
    const float* W1       = (const float*)d_in[2];
    const float* att_src1 = (const float*)d_in[3];
    const float* att_dst1 = (const float*)d_in[4];
    const float* b1       = (const float*)d_in[5];
    const float* W2       = (const float*)d_in[6];
    const float* att_src2 = (const float*)d_in[7];
    const float* att_dst2 = (const float*)d_in[8];
    const float* b2       = (const float*)d_in[9];
    float* out = (float*)d_out;

    const int* src = ei;
    const int* dst = ei + N_EDGES;

    // ---- workspace carve-up (bytes) ----
    char* ws = (char*)d_ws;
    size_t off = 0;
    unsigned short* h1 = (unsigned short*)(ws + off);
    off += (size_t)N_NODES * HID * 2;                                      // 25.6 MB bf16
    float* a_src1 = (float*)(ws + off); off += (size_t)N_NODES * HEADS * 4;
    float* a_dst1 = (float*)(ws + off); off += (size_t)N_NODES * HEADS * 4;
    float* h2  = (float*)(ws + off); off += (size_t)N_NODES * OUT_C * 4;
    float* a2s = (float*)(ws + off); off += (size_t)N_NODES * 4;
    float* a2d = (float*)(ws + off); off += (size_t)N_NODES * 4;
    int* deg    = (int*)(ws + off); off += (size_t)N_NODES * 4;
    int* rowptr = (int*)(ws + off); off += (size_t)(N_NODES + 1) * 4;
    int* cursor = (int*)(ws + off); off += (size_t)N_NODES * 4;
    int* tmp    = (int*)(ws + off); off += (size_t)N_NODES * 4;
    int* bs     = (int*)(ws + off); off += 64 * 4;
    int* csr_src = (int*)(ws + off); off += (size_t)ET * 4;                // 6.6 MB

    hipMemsetAsync(deg, 0, (size_t)N_NODES * 4, stream);

    const int NW = (N_NODES * 64 + 255) / 256;        // wave-per-node grids

    // ---- gemm half A || hist ----
    fusedA_kernel<<<GA + EBLK, 256, 0, stream>>>(
        x, W1, att_src1, att_dst1, h1, a_src1, a_dst1, dst, deg);
    scanA_kernel<<<SB, 1024, 0, stream>>>(deg, tmp, bs);
    scanC_kernel<<<(N_NODES + 255) / 256, 256, 0, stream>>>(tmp, bs, deg, rowptr, cursor);
    // ---- gemm half B || scatter ----
    fusedB_kernel<<<GB + EBLK, 256, 0, stream>>>(
        x, W1, att_src1, att_dst1, h1, a_src1, a_dst1, src, dst, cursor, csr_src);

    // ---- layer 1 aggregate + ELU + layer 2 GEMM (fused) ----
    agg1_fused_kernel<<<NW, 256, 0, stream>>>(
        rowptr, csr_src, a_src1, a_dst1, h1, b1, W2, att_src2, att_dst2,
        h2, a2s, a2d);

    // ---- layer 2 aggregate ----
    agg2_fused_kernel<<<(N_NODES * 16 + 255) / 256, 256, 0, stream>>>(
        rowptr, csr_src, a2s, a2d, h2, b2, out);
}

// Round 7
// 394.353 us; speedup vs baseline: 18.7334x; 1.1129x over previous
//
#include <hip/hip_runtime.h>
#include <hip/hip_bf16.h>
#include <math.h>

#define N_NODES 50000
#define N_EDGES 1600000
#define ET (N_EDGES + N_NODES)   // with self loops
#define IN_C 165
#define HID 256
#define HEADS 8
#define C1 32
#define OUT_C 2
#define NEG_SLOPE 0.2f
#define SB ((N_NODES + 1023) / 1024)       // 49 scan blocks
#define TROWS 32                           // gemm tile rows
#define XSTR 36                            // padded LDS stride (transposed x tile)
#define GEMM_BLOCKS ((N_NODES + TROWS - 1) / TROWS)  // 1563
#define GA (GEMM_BLOCKS / 2)               // 781: gemm blocks co-launched with hist
#define GB (GEMM_BLOCKS - GA)              // 782: gemm blocks co-launched with scatter
#define EBLK ((ET + 255) / 256)            // 6446 edge blocks

__device__ inline float lrelu(float v) { return v > 0.f ? v : NEG_SLOPE * v; }

// fp32 -> bf16 bits, round-to-nearest-even
__device__ inline unsigned short f32_bf16(float f) {
    unsigned u = __float_as_uint(f);
    return (unsigned short)((u + 0x7FFFu + ((u >> 16) & 1u)) >> 16);
}

// ============ shared gemm1+att block body ============
// 32 rows x 256 cols; thread = 4 rows x 8 cols (32 FMA per k).
// x tile staged TRANSPOSED+padded: xs[k*36 + r] -> conflict-free b128 reads.
// h stored packed bf16 (RNE); attention logits fp32 from fp32 accumulators.
__device__ __forceinline__ void gemm1_att_block(
        int row0, const float* __restrict__ x, const float* __restrict__ W,
        const float* __restrict__ att_src, const float* __restrict__ att_dst,
        unsigned short* __restrict__ h, float* __restrict__ a_src,
        float* __restrict__ a_dst,
        float* xs, float* sh_s, float* sh_d) {
    const int tid = threadIdx.x;
    const int nrow = (N_NODES - row0 < TROWS) ? (N_NODES - row0) : TROWS;
    const int lim = nrow * IN_C;
    // stage x transposed: global read is fully coalesced (linear idx)
    for (int idx = tid; idx < TROWS * IN_C; idx += 256) {
        int r = idx / IN_C, k = idx - r * IN_C;
        xs[k * XSTR + r] = (idx < lim) ? x[(size_t)row0 * IN_C + idx] : 0.f;
    }
    __syncthreads();
    const int tr = tid >> 5;                  // 0..7: row group (4 rows)
    const int cq = tid & 31;                  // 0..31: col group (8 cols)
    const int c0 = cq * 8;
    float acc[4][8];
    #pragma unroll
    for (int j = 0; j < 4; ++j)
        #pragma unroll
        for (int q = 0; q < 8; ++q) acc[j][q] = 0.f;
    for (int k = 0; k < IN_C; ++k) {
        float4 xv = *(const float4*)(xs + k * XSTR + tr * 4);  // 4 rows at k
        const float* wp = W + k * HID + c0;
        float4 w0 = *(const float4*)(wp);
        float4 w1 = *(const float4*)(wp + 4);
        #pragma unroll
        for (int j = 0; j < 4; ++j) {
            float xj = (j == 0) ? xv.x : (j == 1) ? xv.y : (j == 2) ? xv.z : xv.w;
            acc[j][0] += xj * w0.x; acc[j][1] += xj * w0.y;
            acc[j][2] += xj * w0.z; acc[j][3] += xj * w0.w;
            acc[j][4] += xj * w1.x; acc[j][5] += xj * w1.y;
            acc[j][6] += xj * w1.z; acc[j][7] += xj * w1.w;
        }
    }
    // store h tile as packed bf16 (8 cols = 16 B = 1 uint4 per row)
    #pragma unroll
    for (int j = 0; j < 4; ++j) {
        int gr = row0 + tr * 4 + j;
        if (gr < N_NODES) {
            unsigned p[4];
            #pragma unroll
            for (int q = 0; q < 4; ++q)
                p[q] = (unsigned)f32_bf16(acc[j][2*q]) |
                       ((unsigned)f32_bf16(acc[j][2*q+1]) << 16);
            *(uint4*)(h + (size_t)gr * HID + c0) = make_uint4(p[0], p[1], p[2], p[3]);
        }
    }
    // fused attention partial dots: cols [c0,c0+8) lie in head cq>>2
    {
        const int hd = cq >> 2;
        const float* as = att_src + hd * C1 + (cq & 3) * 8;
        const float* ad = att_dst + hd * C1 + (cq & 3) * 8;
        float av[8], dv[8];
        #pragma unroll
        for (int q = 0; q < 2; ++q) {
            float4 a4 = *(const float4*)(as + q * 4);
            float4 d4 = *(const float4*)(ad + q * 4);
            av[q*4+0]=a4.x; av[q*4+1]=a4.y; av[q*4+2]=a4.z; av[q*4+3]=a4.w;
            dv[q*4+0]=d4.x; dv[q*4+1]=d4.y; dv[q*4+2]=d4.z; dv[q*4+3]=d4.w;
        }
        #pragma unroll
        for (int j = 0; j < 4; ++j) {
            float ps = 0.f, pd = 0.f;
            #pragma unroll
            for (int q = 0; q < 8; ++q) {
                ps += acc[j][q] * av[q];
                pd += acc[j][q] * dv[q];
            }
            sh_s[(tr * 4 + j) * 32 + cq] = ps;
            sh_d[(tr * 4 + j) * 32 + cq] = pd;
        }
    }
    __syncthreads();
    // reduce 4 col-groups per head: 32 rows x 8 heads = 256 pairs, one/thread
    {
        int r = tid >> 3, hd = tid & 7;
        int gr = row0 + r;
        if (gr < N_NODES) {
            float4 s4 = *(const float4*)(sh_s + r * 32 + hd * 4);
            float4 d4 = *(const float4*)(sh_d + r * 32 + hd * 4);
            a_src[gr * 8 + hd] = (s4.x + s4.y) + (s4.z + s4.w);
            a_dst[gr * 8 + hd] = (d4.x + d4.y) + (d4.z + d4.w);
        }
    }
}

// ============ fused A: gemm half 1 || dst-histogram ============
__global__ __launch_bounds__(256) void fusedA_kernel(
        const float* __restrict__ x, const float* __restrict__ W,
        const float* __restrict__ att_src, const float* __restrict__ att_dst,
        unsigned short* __restrict__ h, float* __restrict__ a_src,
        float* __restrict__ a_dst,
        const int* __restrict__ dst, int* __restrict__ deg) {
    __shared__ float xs[IN_C * XSTR];         // 23.2 KB
    __shared__ float sh_s[TROWS * 32];        // 4 KB
    __shared__ float sh_d[TROWS * 32];        // 4 KB
    if (blockIdx.x < GA) {
        gemm1_att_block(blockIdx.x * TROWS, x, W, att_src, att_dst,
                        h, a_src, a_dst, xs, sh_s, sh_d);
    } else {
        int e = (blockIdx.x - GA) * 256 + threadIdx.x;
        if (e < ET) {
            int d = (e < N_EDGES) ? dst[e] : e - N_EDGES;
            atomicAdd(&deg[d], 1);
        }
    }
}

// ============ CSR scan, stage A ============
__global__ __launch_bounds__(1024) void scanA_kernel(
        const int* __restrict__ deg, int* __restrict__ tmp, int* __restrict__ bs) {
    const int i = blockIdx.x * 1024 + threadIdx.x;
    const int l = threadIdx.x & 63;
    const int w = threadIdx.x >> 6;
    int v = (i < N_NODES) ? deg[i] : 0;
    int sc = v;
    #pragma unroll
    for (int off = 1; off < 64; off <<= 1) {
        int t = __shfl_up(sc, off);
        if (l >= off) sc += t;
    }
    __shared__ int ws[16];
    if (l == 63) ws[w] = sc;
    __syncthreads();
    if (threadIdx.x < 16) {
        int t = ws[threadIdx.x];
        #pragma unroll
        for (int off = 1; off < 16; off <<= 1) {
            int u = __shfl_up(t, off);
            if ((int)threadIdx.x >= off) t += u;
        }
        ws[threadIdx.x] = t;
    }
    __syncthreads();
    int incl = sc + (w > 0 ? ws[w - 1] : 0);
    if (i < N_NODES) tmp[i] = incl;
    if (threadIdx.x == 1023) bs[blockIdx.x] = incl;
}

// ============ CSR scan, stage C: finalize rowptr + cursor ============
__global__ __launch_bounds__(256) void scanC_kernel(
        const int* __restrict__ tmp, const int* __restrict__ bs,
        const int* __restrict__ deg, int* __restrict__ rowptr,
        int* __restrict__ cursor) {
    __shared__ int boff_s[64];
    if (threadIdx.x < 64) {
        int l = threadIdx.x;
        int v = (l < SB) ? bs[l] : 0;
        int sc = v;
        #pragma unroll
        for (int off = 1; off < 64; off <<= 1) {
            int t = __shfl_up(sc, off);
            if (l >= off) sc += t;
        }
        boff_s[l] = sc - v;
    }
    __syncthreads();
    int i = blockIdx.x * 256 + threadIdx.x;
    if (i >= N_NODES) return;
    int incl = tmp[i] + boff_s[i >> 10];
    rowptr[i + 1] = incl;
    cursor[i] = incl - deg[i];
    if (i == 0) rowptr[0] = 0;
}

// ============ fused B: gemm half 2 || scatter ============
__global__ __launch_bounds__(256) void fusedB_kernel(
        const float* __restrict__ x, const float* __restrict__ W,
        const float* __restrict__ att_src, const float* __restrict__ att_dst,
        unsigned short* __restrict__ h, float* __restrict__ a_src,
        float* __restrict__ a_dst,
        const int* __restrict__ src, const int* __restrict__ dst,
        int* __restrict__ cursor, int* __restrict__ csr_src) {
    __shared__ float xs[IN_C * XSTR];
    __shared__ float sh_s[TROWS * 32];
    __shared__ float sh_d[TROWS * 32];
    if (blockIdx.x < GB) {
        gemm1_att_block((GA + blockIdx.x) * TROWS, x, W, att_src, att_dst,
                        h, a_src, a_dst, xs, sh_s, sh_d);
    } else {
        int e = (blockIdx.x - GB) * 256 + threadIdx.x;
        if (e < ET) {
            int s, d;
            if (e < N_EDGES) { s = src[e]; d = dst[e]; } else { s = d = e - N_EDGES; }
            int pos = atomicAdd(&cursor[d], 1);
            csr_src[pos] = s;
        }
    }
}

// ============ Layer 1 fused: softmax-aggregate(bf16 gather) + bias + ELU
//              + layer-2 GEMM.  One wave per dst node; hx never hits memory. ==
__global__ __launch_bounds__(256) void agg1_fused_kernel(
        const int* __restrict__ rowptr, const int* __restrict__ csr_src,
        const float* __restrict__ a_src, const float* __restrict__ a_dst,
        const unsigned short* __restrict__ h1, const float* __restrict__ b1,
        const float* __restrict__ W2,
        const float* __restrict__ as2, const float* __restrict__ ad2,
        float* __restrict__ h2, float* __restrict__ a2s, float* __restrict__ a2d) {
    int wid = (blockIdx.x * 256 + threadIdx.x) >> 6;
    int l = threadIdx.x & 63;
    if (wid >= N_NODES) return;
    int i = rowptr[wid];
    const int end = rowptr[wid + 1];
    const int hp = l >> 3;
    const float ad_p = a_dst[wid * 8 + hp];
    const int c = l * 4;                      // ushort units
    float den = 0.f;
    float ax = 0.f, ay = 0.f, az = 0.f, aw = 0.f;
    for (; i + 8 <= end; i += 8) {
        int s[8];
        #pragma unroll
        for (int j = 0; j < 8; ++j) s[j] = csr_src[i + j];
        uint2 v[8];
        #pragma unroll
        for (int j = 0; j < 8; ++j)
            v[j] = *(const uint2*)(h1 + (size_t)s[j] * HID + c);
        float w[8];
        #pragma unroll
        for (int j = 0; j < 8; ++j)
            w[j] = __expf(lrelu(a_src[s[j] * 8 + hp] + ad_p));
        #pragma unroll
        for (int j = 0; j < 8; ++j) {
            den += w[j];
            ax += w[j] * __uint_as_float(v[j].x << 16);
            ay += w[j] * __uint_as_float(v[j].x & 0xFFFF0000u);
            az += w[j] * __uint_as_float(v[j].y << 16);
            aw += w[j] * __uint_as_float(v[j].y & 0xFFFF0000u);
        }
    }
    for (; i < end; ++i) {
        int s = csr_src[i];
        uint2 v = *(const uint2*)(h1 + (size_t)s * HID + c);
        float w = __expf(lrelu(a_src[s * 8 + hp] + ad_p));
        den += w;
        ax += w * __uint_as_float(v.x << 16);
        ay += w * __uint_as_float(v.x & 0xFFFF0000u);
        az += w * __uint_as_float(v.y << 16);
        aw += w * __uint_as_float(v.y & 0xFFFF0000u);
    }
    const float inv = 1.f / den;
    float4 bv = *(const float4*)(b1 + c);
    float o0 = ax * inv + bv.x, o1 = ay * inv + bv.y;
    float o2 = az * inv + bv.z, o3 = aw * inv + bv.w;
    o0 = o0 > 0.f ? o0 : expm1f(o0);
    o1 = o1 > 0.f ? o1 : expm1f(o1);
    o2 = o2 > 0.f ? o2 : expm1f(o2);
    o3 = o3 > 0.f ? o3 : expm1f(o3);
    // ---- fused layer-2 GEMM: lane owns hx channels c..c+3 ----
    const float* wv = W2 + l * 8;             // rows c..c+3, 2 cols, row-major
    float4 w0 = *(const float4*)(wv);
    float4 w1 = *(const float4*)(wv + 4);
    float p0 = o0 * w0.x + o1 * w0.z + o2 * w1.x + o3 * w1.z;
    float p1 = o0 * w0.y + o1 * w0.w + o2 * w1.y + o3 * w1.w;
    #pragma unroll
    for (int off = 32; off; off >>= 1) {
        p0 += __shfl_down(p0, off);
        p1 += __shfl_down(p1, off);
    }
    if (l == 0) {
        h2[wid * 2]     = p0;
        h2[wid * 2 + 1] = p1;
        a2s[wid] = p0 * as2[0] + p1 * as2[1];
        a2d[wid] = p0 * ad2[0] + p1 * ad2[1];
    }
}

// ============ Layer 2 fused: 16 lanes per node (deg~33), 4 nodes/wave ========
__global__ __launch_bounds__(256) void agg2_fused_kernel(
        const int* __restrict__ rowptr, const int* __restrict__ csr_src,
        const float* __restrict__ a2s, const float* __restrict__ a2d,
        const float* __restrict__ h2, const float* __restrict__ b2,
        float* __restrict__ out) {
    int t = blockIdx.x * 256 + threadIdx.x;
    int node = t >> 4;
    int l = t & 15;
    if (node >= N_NODES) return;
    const int start = rowptr[node];
    const int end = rowptr[node + 1];
    const float adv = a2d[node];
    float sm = 0.f, acc0 = 0.f, acc1 = 0.f;
    for (int i = start + l; i < end; i += 16) {
        int s = csr_src[i];
        float w = __expf(lrelu(a2s[s] + adv));
        sm += w;
        acc0 += w * h2[s * 2];
        acc1 += w * h2[s * 2 + 1];
    }
    #pragma unroll
    for (int off = 8; off; off >>= 1) {
        sm   += __shfl_xor(sm, off);
        acc0 += __shfl_xor(acc0, off);
        acc1 += __shfl_xor(acc1, off);
    }
    if (l == 0) {
        out[node * 2]     = acc0 / sm + b2[0];
        out[node * 2 + 1] = acc1 / sm + b2[1];
    }
}

extern "C" void kernel_launch(void* const* d_in, const int* in_sizes, int n_in,
                              void* d_out, int out_size, void* d_ws, size_t ws_size,
                              hipStream_t stream) {
    (void)in_sizes; (void)n_in; (void)out_size; (void)ws_size;
    const float* x        = (const float*)d_in[0];
    const int*   ei       = (const int*)d_in[1];
    const float* W1       = (const float*)d_in[2];
    const float* att_src1 = (const float*)d_in[3];
    const float* att_dst1 = (const float*)d_in[4];
    const float* b1       = (const float*)d_in[5];
    const float* W2       = (const float*)d_in[6];
    const float* att_src2 = (const float*)d_in[7];
    const float* att_dst2 = (const float*)d_in[8];
    const float* b2       = (const float*)d_in[9];
    float* out = (float*)d_out;

    const int* src = ei;
    const int* dst = ei + N_EDGES;

    // ---- workspace carve-up (bytes) ----
    char* ws = (char*)d_ws;
    size_t off = 0;
    unsigned short* h1 = (unsigned short*)(ws + off);
    off += (size_t)N_NODES * HID * 2;                                      // 25.6 MB bf16
    float* a_src1 = (float*)(ws + off); off += (size_t)N_NODES * HEADS * 4;
    float* a_dst1 = (float*)(ws + off); off += (size_t)N_NODES * HEADS * 4;
    float* h2  = (float*)(ws + off); off += (size_t)N_NODES * OUT_C * 4;
    float* a2s = (float*)(ws + off); off += (size_t)N_NODES * 4;
    float* a2d = (float*)(ws + off); off += (size_t)N_NODES * 4;
    int* deg    = (int*)(ws + off); off += (size_t)N_NODES * 4;
    int* rowptr = (int*)(ws + off); off += (size_t)(N_NODES + 1) * 4;
    int* cursor = (int*)(ws + off); off += (size_t)N_NODES * 4;
    int* tmp    = (int*)(ws + off); off += (size_t)N_NODES * 4;
    int* bs     = (int*)(ws + off); off += 64 * 4;
    int* csr_src = (int*)(ws + off); off += (size_t)ET * 4;                // 6.6 MB

    hipMemsetAsync(deg, 0, (size_t)N_NODES * 4, stream);

    const int NW = (N_NODES * 64 + 255) / 256;        // wave-per-node grids

    // ---- gemm half A || hist ----
    fusedA_kernel<<<GA + EBLK, 256, 0, stream>>>(
        x, W1, att_src1, att_dst1, h1, a_src1, a_dst1, dst, deg);
    scanA_kernel<<<SB, 1024, 0, stream>>>(deg, tmp, bs);
    scanC_kernel<<<(N_NODES + 255) / 256, 256, 0, stream>>>(tmp, bs, deg, rowptr, cursor);
    // ---- gemm half B || scatter ----
    fusedB_kernel<<<GB + EBLK, 256, 0, stream>>>(
        x, W1, att_src1, att_dst1, h1, a_src1, a_dst1, src, dst, cursor, csr_src);

    // ---- layer 1 aggregate + ELU + layer 2 GEMM (fused) ----
    agg1_fused_kernel<<<NW, 256, 0, stream>>>(
        rowptr, csr_src, a_src1, a_dst1, h1, b1, W2, att_src2, att_dst2,
        h2, a2s, a2d);

    // ---- layer 2 aggregate ----
    agg2_fused_kernel<<<(N_NODES * 16 + 255) / 256, 256, 0, stream>>>(
        rowptr, csr_src, a2s, a2d, h2, b2, out);
}